// Round 10
// baseline (98.770 us; speedup 1.0000x reference)
//
#include <hip/hip_runtime.h>
#include <hip/hip_bf16.h>

typedef __attribute__((ext_vector_type(4))) float f32x4;
typedef __attribute__((ext_vector_type(2))) unsigned int u32x2;
typedef __attribute__((ext_vector_type(4))) unsigned int u32x4;
typedef __attribute__((ext_vector_type(8))) short bf16x8;

#define EPSF 1e-7f

__device__ __forceinline__ float radial_factor(float sumsq, float c, float s){
  float sc = sqrtf(c);
  float nv = sqrtf(sumsq);
  float nu = fmaxf(s*nv, EPSF);
  float th = tanhf(sc*nu);
  float r1 = th/sc;
  float maxn = (1.0f - 1e-5f)/sc;
  float r2 = fminf(r1, maxn);
  float n1 = fmaxf(r2, EPSF);
  float a  = fminf(sc*n1, 1.0f - 1e-7f);
  float r3 = 0.5f*logf((1.0f + a)/(1.0f - a));
  return r3*r2/(sc*n1*nu);
}

__device__ __forceinline__ float gelu_f(float x){
  return 0.5f*x*(1.0f + erff(x*0.70710678118654752f));
}

__device__ __forceinline__ unsigned f2bf1(float f){
  unsigned u = __float_as_uint(f);
  return (u + 0x7FFFu + ((u>>16)&1u)) >> 16;
}
__device__ __forceinline__ unsigned f2bf_pk(float lo, float hi){
  unsigned ul = f2bf1(lo);
  unsigned uh = __float_as_uint(hi);
  uh = (uh + 0x7FFFu + ((uh>>16)&1u)) & 0xFFFF0000u;
  return ul | uh;
}

// async global->LDS, 16B per lane; LDS dest is wave-uniform base + lane*16 (linear fill)
__device__ __forceinline__ void gload_lds16(const void* g, void* l){
  __builtin_amdgcn_global_load_lds((const __attribute__((address_space(1))) unsigned int*)g,
                                   (__attribute__((address_space(3))) unsigned int*)l,
                                   16, 0, 0);
}

// ---------------- workspace layout (bytes) ----------------
#define WS_WC     0          // bf16 25*2048 elts = 102400 B (swizzled slabs)
#define WS_BCOMB  204800     // f32 [64]
#define WS_W0AE   205056     // f32 [32][64]
#define WS_BROT0  213248     // f32 [5][64]
#define WS_BOWN0  214528     // f32 [5][64]
#define WS_W0AT   215808     // f32 [64][32]
#define WS_MB0    224000     // f32 [64]
#define WS_MB1    224256     // f32 [4]
#define WS_W1AE   224272     // f32 [16][4]
#define WS_ZERO   224528     // f32 [16] zeros
#define WS_V      225280     // f32 [B][64]
#define WS_V2     17002496   // f32 [B/4][64] scratch for attribution dispatch

// ============ prep A: W_comb (blocks 0..49, swizzled store) + exp row-actions ============
__global__ __launch_bounds__(256) void prep_a(
    const float* __restrict__ W_in, const float* __restrict__ b_in,
    const float* __restrict__ W_tan, const float* __restrict__ b_tan,
    const float* __restrict__ A_rot, const float* __restrict__ W0a,
    const float* __restrict__ bp0,
    unsigned short* __restrict__ Wc, float* __restrict__ bcomb,
    float* __restrict__ W0aE, float* __restrict__ brot0, float* __restrict__ bown0)
{
  __shared__ __align__(16) float Al[64][68];
  __shared__ __align__(16) float ST[64][68];
  const int bid = blockIdx.x, t = threadIdx.x;

  if (bid < 50){
    if (bid == 0 && t < 64){
      float s = b_tan[t];
      for (int j = 0; j < 128; ++j) s += b_in[j]*W_tan[t*128+j];
      bcomb[t] = s;
    }
    const int g4 = bid*256 + t;              // 0..12799
    const int n = g4/200, k4 = (g4 - n*200)*4;   // k4 in [0,800)
    f32x4 s = {0.f,0.f,0.f,0.f};
    if (k4 < 784){
      for (int j = 0; j < 128; ++j){
        float wt = W_tan[n*128+j];
        f32x4 wi = *(const f32x4*)(W_in + j*784 + k4);
        s += wt*wi;
      }
    }
    u32x2 st = { f2bf_pk(s[0], s[1]), f2bf_pk(s[2], s[3]) };
    const int tsl = k4 >> 5;
    const int q   = (k4 >> 3) & 3;
    const int qp  = q ^ ((n >> 1) & 3);
    const int idx = tsl*2048 + n*32 + qp*8 + (k4 & 7);
    *(u32x2*)(Wc + idx) = st;
  } else {
    for (int m = t; m < 4096; m += 256){
      int r = m >> 6, c = m & 63;
      Al[r][c] = A_rot[m];
    }
    __syncthreads();
    for (int m = t; m < 4096; m += 256){
      int r = m >> 6, c = m & 63;
      ST[r][c] = Al[c][r] - Al[r][c];
    }
    __syncthreads();
    const int wv = t >> 6, lane = t & 63;
    const int row = (bid - 50)*4 + wv;
    if (row < 37){
      float v, sgn;
      if (row < 32){ v = W0a[row*64 + lane]; sgn = 1.f; }
      else {
        const int r = row - 32;
        float b = bp0[r*64 + lane];
        float ssq = b*b;
        #pragma unroll
        for (int d = 1; d < 64; d <<= 1) ssq += __shfl_xor(ssq, d);
        float fc = radial_factor(ssq, 1.0f, 1.0f);
        v = b*fc;
        bown0[r*64 + lane] = v;
        sgn = -1.f;
      }
      float acc = v;
      for (int k = 1; k <= 12; ++k){
        const float coef = sgn/(float)k;
        float nv = 0.f;
        #pragma unroll
        for (int m = 0; m < 64; m += 4){
          f32x4 s4 = *(const f32x4*)&ST[lane][m];
          nv += __int_as_float(__builtin_amdgcn_readlane(__float_as_int(v), m+0))*s4[0];
          nv += __int_as_float(__builtin_amdgcn_readlane(__float_as_int(v), m+1))*s4[1];
          nv += __int_as_float(__builtin_amdgcn_readlane(__float_as_int(v), m+2))*s4[2];
          nv += __int_as_float(__builtin_amdgcn_readlane(__float_as_int(v), m+3))*s4[3];
        }
        nv *= coef;
        v = nv; acc += nv;
      }
      if (row < 32) W0aE[row*64 + lane] = acc;
      else          brot0[(row-32)*64 + lane] = acc;
    }
  }
}

// ============ prep B: small folds (1 block x 256) ============
__global__ __launch_bounds__(256) void prep_small(
    const float* __restrict__ bp1,
    const float* __restrict__ p_quat, const float* __restrict__ q_quat,
    const float* __restrict__ b0a, const float* __restrict__ W0b, const float* __restrict__ b0b,
    const float* __restrict__ W1a,
    const float* __restrict__ W0aE, const float* __restrict__ brot0, const float* __restrict__ bown0,
    float* __restrict__ W0aT, float* __restrict__ mb0, float* __restrict__ mb1,
    float* __restrict__ W1aE, float* __restrict__ zerog)
{
  __shared__ float g[5][32];
  __shared__ float c1[5][4];
  __shared__ float fac1[3];
  __shared__ float Mq[4][4];
  const int t = threadIdx.x;

  for (int i = t; i < 2048; i += 256){
    int o = i >> 6, k = i & 63;
    W0aT[k*32 + o] = W0aE[i];
  }
  if (t >= 240) zerog[t - 240] = 0.f;
  if (t < 64){
    float s = 0.f;
    for (int r = 0; r < 5; ++r) s += bown0[r*64 + t];
    mb0[t] = s * 0.2f;
  }
  if (t < 160){
    int r = t >> 5, o = t & 31;
    float s = b0a[o];
    for (int k = 0; k < 64; ++k) s += brot0[r*64+k]*W0aE[o*64+k];
    g[r][o] = gelu_f(s);
  }
  if (t >= 192 && t < 195){
    int r = t - 192;
    float ssq = 0.f;
    for (int j = 0; j < 4; ++j){ float b = bp1[r*4+j]; ssq += b*b; }
    fac1[r] = radial_factor(ssq, 0.8f, 1.0f);
  }
  if (t == 224){
    float pw=p_quat[0],px=p_quat[1],py=p_quat[2],pz=p_quat[3];
    float n1 = sqrtf(pw*pw+px*px+py*py+pz*pz) + EPSF;
    pw/=n1; px/=n1; py/=n1; pz/=n1;
    float qw=q_quat[0],qx=q_quat[1],qy=q_quat[2],qz=q_quat[3];
    float n2 = sqrtf(qw*qw+qx*qx+qy*qy+qz*qz) + EPSF;
    qw/=n2; qx/=n2; qy/=n2; qz/=n2;
    float Lp[4][4] = {{pw,-px,-py,-pz},{px,pw,-pz,py},{py,pz,pw,-px},{pz,-py,px,pw}};
    float Rq[4][4] = {{qw,-qx,-qy,-qz},{qx,qw,qz,-qy},{qy,-qz,qw,qx},{qz,qy,-qx,qw}};
    #pragma unroll
    for (int i = 0; i < 4; ++i)
      #pragma unroll
      for (int k = 0; k < 4; ++k){
        float s = 0.f;
        #pragma unroll
        for (int m = 0; m < 4; ++m) s += Rq[i][m]*Lp[m][k];
        Mq[i][k] = s;
      }
  }
  __syncthreads();
  if (t < 20){
    int r = t >> 2, o = t & 3;
    float s = b0b[o];
    for (int k = 0; k < 32; ++k) s += g[r][k]*W0b[o*32+k];
    c1[r][o] = s;
  }
  __syncthreads();
  if (t < 4){
    float s = 0.f;
    for (int r = 0; r < 3; ++r) s += bp1[r*4+t]*fac1[r];
    for (int r = 0; r < 5; ++r) s += c1[r][t];
    mb1[t] = s * 0.125f;
  }
  if (t >= 64 && t < 128){
    int i = t - 64, o = i >> 2, kq = i & 3;
    float s = 0.f;
    #pragma unroll
    for (int j = 0; j < 4; ++j) s += W1a[o*4+j]*Mq[j][kq];
    W1aE[o*4+kq] = s;
  }
}

// ============ kernel 1: GEMM, depth-3 counted-vmcnt pipeline ============
__global__ __launch_bounds__(256, 4) void gemm_v(
    const float* __restrict__ x,
    const unsigned short* __restrict__ Wcs,
    const float* __restrict__ bcomb,
    const float* __restrict__ zerog,
    float* __restrict__ v)
{
  __shared__ __align__(16) char smem[36864];
  char* xsB  = smem;           // [3][8192]
  char* wcsB = smem + 24576;   // [3][4096]

  const int tid  = threadIdx.x;
  const int lane = tid & 63;
  const int w    = tid >> 6;
  const int wr   = w >> 1, wc = w & 1;
  const int lr   = lane & 15, lkg = lane >> 4;
  const size_t rowBase = (size_t)blockIdx.x * 64;

  const int row8 = lane >> 3;
  const int qs   = lane & 7;
  const int qoff = qs ^ row8;
  const float* xsrcA = x + (rowBase + (size_t)(8*w     + row8))*784 + qoff*4;
  const float* xsrcB = x + (rowBase + (size_t)(8*(w+4) + row8))*784 + qoff*4;
  const unsigned short* wsrc = Wcs + (16*w + (lane>>2))*32 + (lane&3)*8;

  const int rA0 = wr*32 + lr;
  const int sA0 = (2*lkg)     ^ (lr & 7);
  const int sA1 = (2*lkg + 1) ^ (lr & 7);
  const int offA00 = rA0*128 + sA0*16;
  const int offA01 = rA0*128 + sA1*16;
  const int rB0 = wc*32 + lr;
  const int sB  = lkg ^ ((rB0 >> 1) & 3);
  const int offB0 = rB0*64 + sB*16;

#define STAGE(slab, buf) do{                                                   \
    const int ks_ = (slab)*32;                                                 \
    char* xd_ = xsB  + (buf)*8192;                                             \
    char* wd_ = wcsB + (buf)*4096;                                             \
    const float* sa_ = (ks_ + qoff*4 < 784) ? (xsrcA + ks_) : zerog;           \
    const float* sb_ = (ks_ + qoff*4 < 784) ? (xsrcB + ks_) : zerog;           \
    gload_lds16(sa_, xd_ + w*1024);                                            \
    gload_lds16(sb_, xd_ + (w+4)*1024);                                        \
    gload_lds16(wsrc + (size_t)(slab)*2048, wd_ + w*1024);                     \
  }while(0)

  f32x4 acc00 = {}, acc01 = {}, acc10 = {}, acc11 = {};

#define BODY(tt, VMSTR) do{                                                    \
    asm volatile("s_waitcnt " VMSTR ::: "memory");                             \
    __builtin_amdgcn_sched_barrier(0);                                         \
    __builtin_amdgcn_s_barrier();                                              \
    const int cur_ = (tt) % 3;                                                 \
    const char* xb_ = xsB  + cur_*8192;                                        \
    const char* wb_ = wcsB + cur_*4096;                                        \
    f32x4 a00_ = *(const f32x4*)(xb_ + offA00);                                \
    f32x4 a01_ = *(const f32x4*)(xb_ + offA01);                                \
    f32x4 a10_ = *(const f32x4*)(xb_ + offA00 + 2048);                         \
    f32x4 a11_ = *(const f32x4*)(xb_ + offA01 + 2048);                         \
    bf16x8 b0_ = *(const bf16x8*)(wb_ + offB0);                                \
    bf16x8 b1_ = *(const bf16x8*)(wb_ + offB0 + 1024);                         \
    u32x4 pk0_ = { f2bf_pk(a00_[0],a00_[1]), f2bf_pk(a00_[2],a00_[3]),         \
                   f2bf_pk(a01_[0],a01_[1]), f2bf_pk(a01_[2],a01_[3]) };       \
    u32x4 pk1_ = { f2bf_pk(a10_[0],a10_[1]), f2bf_pk(a10_[2],a10_[3]),         \
                   f2bf_pk(a11_[0],a11_[1]), f2bf_pk(a11_[2],a11_[3]) };       \
    bf16x8 af0_ = __builtin_bit_cast(bf16x8, pk0_);                            \
    bf16x8 af1_ = __builtin_bit_cast(bf16x8, pk1_);                            \
    acc00 = __builtin_amdgcn_mfma_f32_16x16x32_bf16(af0_, b0_, acc00, 0,0,0);  \
    acc01 = __builtin_amdgcn_mfma_f32_16x16x32_bf16(af0_, b1_, acc01, 0,0,0);  \
    acc10 = __builtin_amdgcn_mfma_f32_16x16x32_bf16(af1_, b0_, acc10, 0,0,0);  \
    acc11 = __builtin_amdgcn_mfma_f32_16x16x32_bf16(af1_, b1_, acc11, 0,0,0);  \
    asm volatile("s_waitcnt lgkmcnt(0)" ::: "memory");                         \
    __builtin_amdgcn_sched_barrier(0);                                         \
    __builtin_amdgcn_s_barrier();                                              \
    if ((tt) + 3 < 25) STAGE((tt)+3, cur_);                                    \
  }while(0)

  STAGE(0, 0); STAGE(1, 1); STAGE(2, 2);

  for (int t = 0; t < 23; ++t)
    BODY(t, "vmcnt(6)");
  BODY(23, "vmcnt(3)");
  BODY(24, "vmcnt(0)");

#undef BODY
#undef STAGE

  {
    f32x4 accA[2][2] = { {acc00, acc01}, {acc10, acc11} };
    #pragma unroll
    for (int fj = 0; fj < 2; ++fj){
      const int col = wc*32 + fj*16 + lr;
      const float bc = bcomb[col];
      #pragma unroll
      for (int fi = 0; fi < 2; ++fi){
        const int r0 = wr*32 + fi*16 + lkg*4;
        #pragma unroll
        for (int j = 0; j < 4; ++j)
          v[(rowBase + (size_t)(r0 + j))*64 + col] = accA[fi][fj][j] + bc;
      }
    }
  }
}

// ============ kernel 2: row phase, 38.3KB LDS -> 4 blocks/CU ============
__global__ __launch_bounds__(256, 4) void row_phase(
    const float* __restrict__ vg,
    const float* __restrict__ W0aT,
    const float* __restrict__ mb0g, const float* __restrict__ mb1g,
    const float* __restrict__ W1aEg,
    const float* __restrict__ b0a, const float* __restrict__ W0b, const float* __restrict__ b0b,
    const float* __restrict__ b1a, const float* __restrict__ W1b, const float* __restrict__ b1b,
    const float* __restrict__ Wout, const float* __restrict__ bout,
    float* __restrict__ out)
{
  __shared__ __align__(16) char smem[38304];
  float* vlds   = (float*)smem;                    // stride 76
  float* gv     = (float*)(smem + 19456);          // stride 36
  float* cW0aTS = (float*)(smem + 28672);          // [64][32] (phase R2)
  float* g1     = (float*)(smem + 28672);          // stride 20 (phase R4+)
  float* cW1bS  = (float*)(smem + 33792);          // [32][16] (phase R5)
  float* cmb0S  = (float*)(smem + 36864);
  float* cW0bS  = (float*)(smem + 37120);
  float* cW1aES = (float*)(smem + 37632);
  float* cb0aS  = (float*)(smem + 37888);
  float* cb0bS  = (float*)(smem + 38016);
  float* cmb1S  = (float*)(smem + 38032);
  float* cb1aS  = (float*)(smem + 38048);
  float* cb1bS  = (float*)(smem + 38112);
  float* cboutS = (float*)(smem + 38240);

  const int tid = threadIdx.x;
  const size_t rowBase = (size_t)blockIdx.x * 64;

  for (int i = tid; i < 1024; i += 256){
    const int r = i >> 4, seg = i & 15;
    *(f32x4*)&vlds[r*76 + seg*4] = *(const f32x4*)(vg + (rowBase + (size_t)r)*64 + seg*4);
  }
  for (int i = tid; i < 2048; i += 256) cW0aTS[i] = W0aT[i];
  if (tid < 64)  cmb0S[tid] = mb0g[tid];
  if (tid < 32)  cb0aS[tid] = b0a[tid];
  if (tid < 128) cW0bS[tid] = W0b[tid];
  if (tid < 4)   { cb0bS[tid] = b0b[tid]; cmb1S[tid] = mb1g[tid]; }
  if (tid < 64)  cW1aES[tid] = W1aEg[tid];
  if (tid < 16)  cb1aS[tid] = b1a[tid];
  if (tid < 32)  cb1bS[tid] = b1b[tid];
  if (tid < 10)  cboutS[tid] = bout[tid];
  __syncthreads();

  const int row = tid >> 2, p4 = tid & 3;

  // R1: v_tan0 = radial(v)  (in place)
  {
    f32x4 rv[4];
    float* vptr = &vlds[row*76 + p4*16];
    #pragma unroll
    for (int i = 0; i < 4; ++i) rv[i] = ((const f32x4*)vptr)[i];
    float ssq = 0.f;
    #pragma unroll
    for (int i = 0; i < 4; ++i)
      ssq += rv[i][0]*rv[i][0] + rv[i][1]*rv[i][1] + rv[i][2]*rv[i][2] + rv[i][3]*rv[i][3];
    ssq += __shfl_xor(ssq, 1); ssq += __shfl_xor(ssq, 2);
    const float fac = radial_factor(ssq, 1.0f, 1.0f);
    #pragma unroll
    for (int i = 0; i < 4; ++i){ rv[i] *= fac; ((f32x4*)vptr)[i] = rv[i]; }
  }
  __syncthreads();

  // R2: a0 = W0aE @ (2*vt0 - mb0) + b0a ; g0 = gelu(a0)
  {
    const int og = p4;
    float a0o[8];
    #pragma unroll
    for (int j = 0; j < 8; ++j) a0o[j] = cb0aS[og*8 + j];
    #pragma unroll 4
    for (int k = 0; k < 64; k += 4){
      f32x4 vtv = *(const f32x4*)&vlds[row*76 + k];
      f32x4 mm  = *(const f32x4*)&cmb0S[k];
      #pragma unroll
      for (int u = 0; u < 4; ++u){
        const float vc = 2.f*vtv[u] - mm[u];
        const f32x4* wp = (const f32x4*)&cW0aTS[(k+u)*32 + og*8];
        f32x4 w0 = wp[0], w1 = wp[1];
        #pragma unroll
        for (int j = 0; j < 4; ++j){ a0o[j] += w0[j]*vc; a0o[4+j] += w1[j]*vc; }
      }
    }
    #pragma unroll
    for (int j = 0; j < 8; ++j) gv[row*36 + og*8 + j] = gelu_f(a0o[j]);
  }
  __syncthreads();

  // R3: v1 = W0b@g0 + b0b; v_tan1, v_comb1
  {
    const int o1 = p4;
    float a1 = cb0bS[o1];
    #pragma unroll
    for (int k = 0; k < 32; k += 4){
      f32x4 gg = *(const f32x4*)&gv[row*36 + k];
      f32x4 ww = *(const f32x4*)&cW0bS[o1*32 + k];
      a1 += gg[0]*ww[0] + gg[1]*ww[1] + gg[2]*ww[2] + gg[3]*ww[3];
    }
    float ss1 = a1*a1;
    ss1 += __shfl_xor(ss1, 1); ss1 += __shfl_xor(ss1, 2);
    const float f1v = radial_factor(ss1, 0.8f, 0.8f);
    const float vt1 = a1*f1v;
    vlds[row*76 + 64 + o1] = vt1;
    vlds[row*76 + 68 + o1] = 2.f*vt1 - cmb1S[o1];
  }
  __syncthreads();

  // R4: a1 = W1aE @ vc1 + b1a ; g1 = gelu   (+ stage cW1b into dead cW0aT tail)
  for (int i = tid; i < 512; i += 256) cW1bS[i] = W1b[i];
  {
    const f32x4 vc1 = *(const f32x4*)&vlds[row*76 + 68];
    #pragma unroll
    for (int j = 0; j < 4; ++j){
      const int o = p4*4 + j;
      float s1 = cb1aS[o] + cW1aES[o*4+0]*vc1[0] + cW1aES[o*4+1]*vc1[1]
                          + cW1aES[o*4+2]*vc1[2] + cW1aES[o*4+3]*vc1[3];
      g1[row*20 + o] = gelu_f(s1);
    }
  }
  __syncthreads();

  // R5: v2 = W1b@g1 + b1b; v_tan2 -> gv
  {
    float v2[8]; float ss2 = 0.f;
    #pragma unroll
    for (int j = 0; j < 8; ++j){
      const int o = p4*8 + j;
      float s = cb1bS[o];
      #pragma unroll
      for (int k = 0; k < 16; k += 4){
        f32x4 gg = *(const f32x4*)&g1[row*20 + k];
        f32x4 ww = *(const f32x4*)&cW1bS[o*16 + k];
        s += gg[0]*ww[0] + gg[1]*ww[1] + gg[2]*ww[2] + gg[3]*ww[3];
      }
      v2[j] = s; ss2 += s*s;
    }
    ss2 += __shfl_xor(ss2, 1); ss2 += __shfl_xor(ss2, 2);
    const float f2v = radial_factor(ss2, 1.2f, 0.6f);
    #pragma unroll
    for (int j = 0; j < 8; ++j) gv[row*36 + p4*8 + j] = v2[j]*f2v;
  }
  __syncthreads();

  // R6: out = W_out @ concat(vt0, vt1, vt2) + b_out   (Wout from L2)
  for (int idx = tid; idx < 640; idx += 256){
    const int r6 = idx/10, o = idx - r6*10;
    float s = cboutS[o];
    const float* wrow = Wout + o*100;
    const float* vrow = &vlds[r6*76];
    #pragma unroll 4
    for (int k = 0; k < 68; k += 4){
      f32x4 a = *(const f32x4*)(vrow + k);
      f32x4 b = *(const f32x4*)(wrow + k);
      s += a[0]*b[0] + a[1]*b[1] + a[2]*b[2] + a[3]*b[3];
    }
    const float* v2row = &gv[r6*36];
    #pragma unroll 4
    for (int k = 0; k < 32; k += 4){
      f32x4 a = *(const f32x4*)(v2row + k);
      f32x4 b = *(const f32x4*)(wrow + 68 + k);
      s += a[0]*b[0] + a[1]*b[1] + a[2]*b[2] + a[3]*b[3];
    }
    out[(rowBase + (size_t)r6)*10 + o] = s;
  }
}

extern "C" void kernel_launch(void* const* d_in, const int* in_sizes, int n_in,
                              void* d_out, int out_size, void* d_ws, size_t ws_size,
                              hipStream_t stream)
{
  (void)n_in; (void)out_size;
  const float* x      = (const float*)d_in[0];
  const float* W_in   = (const float*)d_in[1];
  const float* b_in   = (const float*)d_in[2];
  const float* W_tan  = (const float*)d_in[3];
  const float* b_tan  = (const float*)d_in[4];
  const float* bp0    = (const float*)d_in[5];
  const float* bp1    = (const float*)d_in[6];
  /* bp2 = d_in[7] — dead in reference */
  const float* A_rot  = (const float*)d_in[8];
  const float* p_quat = (const float*)d_in[9];
  const float* q_quat = (const float*)d_in[10];
  const float* W0a    = (const float*)d_in[11];
  const float* b0a    = (const float*)d_in[12];
  const float* W0b    = (const float*)d_in[13];
  const float* b0b    = (const float*)d_in[14];
  const float* W1a    = (const float*)d_in[15];
  const float* b1a    = (const float*)d_in[16];
  const float* W1b    = (const float*)d_in[17];
  const float* b1b    = (const float*)d_in[18];
  const float* W_out  = (const float*)d_in[19];
  const float* b_out  = (const float*)d_in[20];

  char* ws = (char*)d_ws;
  unsigned short* Wcs = (unsigned short*)(ws + WS_WC);
  float* bcomb = (float*)(ws + WS_BCOMB);
  float* W0aE  = (float*)(ws + WS_W0AE);
  float* brot0 = (float*)(ws + WS_BROT0);
  float* bown0 = (float*)(ws + WS_BOWN0);
  float* W0aT  = (float*)(ws + WS_W0AT);
  float* mb0   = (float*)(ws + WS_MB0);
  float* mb1   = (float*)(ws + WS_MB1);
  float* W1aE  = (float*)(ws + WS_W1AE);
  float* zerog = (float*)(ws + WS_ZERO);
  float* vbuf  = (float*)(ws + WS_V);
  float* vbuf2 = (float*)(ws + WS_V2);

  const int Brows = in_sizes[0] / 784;
  const int nblk  = Brows / 64;
  const int nblk4 = nblk / 4;

  prep_a<<<60, 256, 0, stream>>>(W_in, b_in, W_tan, b_tan, A_rot, W0a, bp0,
                                 Wcs, bcomb, W0aE, brot0, bown0);
  prep_small<<<1, 256, 0, stream>>>(bp1, p_quat, q_quat, b0a, W0b, b0b, W1a,
                                    W0aE, brot0, bown0, W0aT, mb0, mb1, W1aE, zerog);
  gemm_v<<<nblk, 256, 0, stream>>>(x, Wcs, bcomb, zerog, vbuf);
  row_phase<<<nblk, 256, 0, stream>>>(vbuf, W0aT, mb0, mb1, W1aE,
                                      b0a, W0b, b0b, b1a, W1b, b1b,
                                      W_out, b_out, (float*)d_out);
  // ---- attribution dispatch (R10): 1/4-grid duplicate GEMM into dead scratch.
  // dur_us delta vs R9 == gemm_v_steady/4 + ~1 us. Output never read.
  if (nblk4 > 0 && ws_size >= (size_t)WS_V2 + (size_t)nblk4 * 64 * 64 * 4){
    gemm_v<<<nblk4, 256, 0, stream>>>(x, Wcs, bcomb, zerog, vbuf2);
  }
}

// Round 11
// 94.377 us; speedup vs baseline: 1.0465x; 1.0465x over previous
//
#include <hip/hip_runtime.h>
#include <hip/hip_bf16.h>

typedef __attribute__((ext_vector_type(4))) float f32x4;
typedef __attribute__((ext_vector_type(2))) unsigned int u32x2;
typedef __attribute__((ext_vector_type(4))) unsigned int u32x4;
typedef __attribute__((ext_vector_type(8))) short bf16x8;

#define EPSF 1e-7f

__device__ __forceinline__ float radial_factor(float sumsq, float c, float s){
  float sc = sqrtf(c);
  float nv = sqrtf(sumsq);
  float nu = fmaxf(s*nv, EPSF);
  float th = tanhf(sc*nu);
  float r1 = th/sc;
  float maxn = (1.0f - 1e-5f)/sc;
  float r2 = fminf(r1, maxn);
  float n1 = fmaxf(r2, EPSF);
  float a  = fminf(sc*n1, 1.0f - 1e-7f);
  float r3 = 0.5f*logf((1.0f + a)/(1.0f - a));
  return r3*r2/(sc*n1*nu);
}

__device__ __forceinline__ float gelu_f(float x){
  return 0.5f*x*(1.0f + erff(x*0.70710678118654752f));
}

__device__ __forceinline__ unsigned f2bf1(float f){
  unsigned u = __float_as_uint(f);
  return (u + 0x7FFFu + ((u>>16)&1u)) >> 16;
}
__device__ __forceinline__ unsigned f2bf_pk(float lo, float hi){
  unsigned ul = f2bf1(lo);
  unsigned uh = __float_as_uint(hi);
  uh = (uh + 0x7FFFu + ((uh>>16)&1u)) & 0xFFFF0000u;
  return ul | uh;
}

__device__ __forceinline__ void gload_lds16(const void* g, void* l){
  __builtin_amdgcn_global_load_lds((const __attribute__((address_space(1))) unsigned int*)g,
                                   (__attribute__((address_space(3))) unsigned int*)l,
                                   16, 0, 0);
}

// ---------------- workspace layout (bytes) ----------------
#define WS_WC     0          // bf16 25*2048 elts (swizzled slabs)
#define WS_BCOMB  204800     // f32 [64]
#define WS_W0AE   205056     // f32 [32][64]
#define WS_BROT0  213248     // f32 [5][64]
#define WS_BOWN0  214528     // f32 [5][64]
#define WS_ZERO   224528     // f32 [16] zeros
#define WS_V      225280     // f32 [B][64]

// ============ prep A: blocks 0..12 = W_comb chunks (LDS-tiled); 13..22 = exp rows ============
__global__ __launch_bounds__(256) void prep_a(
    const float* __restrict__ W_in, const float* __restrict__ b_in,
    const float* __restrict__ W_tan, const float* __restrict__ b_tan,
    const float* __restrict__ A_rot, const float* __restrict__ W0a,
    const float* __restrict__ bp0,
    unsigned short* __restrict__ Wc, float* __restrict__ bcomb,
    float* __restrict__ W0aE, float* __restrict__ brot0, float* __restrict__ bown0,
    float* __restrict__ zerog)
{
  __shared__ __align__(16) float Wt[64][132];   // W_tan (pad for bank spread)
  __shared__ __align__(16) float Wi[128][68];   // W_in k-chunk (64 cols, zero-padded)
  __shared__ float bin[128];
  __shared__ __align__(16) float Al[64][68];
  __shared__ __align__(16) float ST[64][68];
  const int bid = blockIdx.x, t = threadIdx.x;

  if (bid < 13){
    const int c = bid;                      // k-chunk: cols c*64 .. c*64+63
    // stage W_tan [64][128] (coalesced f32x4)
    for (int i = t; i < 2048; i += 256){
      const int n = i >> 5, s4 = i & 31;
      *(f32x4*)&Wt[n][s4*4] = *(const f32x4*)(W_tan + n*128 + s4*4);
    }
    // stage W_in chunk [128][64] with zero pad past col 784
    for (int i = t; i < 2048; i += 256){
      const int j = i >> 4, s4 = i & 15;
      const int col = c*64 + s4*4;
      f32x4 v = {0.f,0.f,0.f,0.f};
      if (col < 784) v = *(const f32x4*)(W_in + j*784 + col);
      *(f32x4*)&Wi[j][s4*4] = v;
    }
    if (c == 0 && t < 128) bin[t] = b_in[t];
    __syncthreads();

    // compute: 4 output items per thread, all operands in LDS
    const int q  = t & 15;                  // col quad within chunk
    const int nb = t >> 4;
    #pragma unroll
    for (int i = 0; i < 4; ++i){
      const int n = nb*4 + i;
      f32x4 acc = {0.f,0.f,0.f,0.f};
      #pragma unroll 4
      for (int j = 0; j < 128; ++j)
        acc += Wt[n][j] * *(const f32x4*)&Wi[j][q*4];
      const int k4 = c*64 + q*4;
      if (k4 < 800){
        u32x2 st = { f2bf_pk(acc[0], acc[1]), f2bf_pk(acc[2], acc[3]) };
        const int tsl = k4 >> 5;
        const int qq  = (k4 >> 3) & 3;
        const int qp  = qq ^ ((n >> 1) & 3);
        const int idx = tsl*2048 + n*32 + qp*8 + (k4 & 7);
        *(u32x2*)(Wc + idx) = st;
      }
    }
    // bcomb = b_tan + W_tan @ b_in  (from LDS)
    if (c == 0 && t < 64){
      float s = b_tan[t];
      for (int j = 0; j < 128; ++j) s += bin[j]*Wt[t][j];
      bcomb[t] = s;
    }
  } else {
    if (bid == 13 && t < 16) zerog[t] = 0.f;
    for (int m = t; m < 4096; m += 256){
      int r = m >> 6, cc = m & 63;
      Al[r][cc] = A_rot[m];
    }
    __syncthreads();
    for (int m = t; m < 4096; m += 256){
      int r = m >> 6, cc = m & 63;
      ST[r][cc] = Al[cc][r] - Al[r][cc];
    }
    __syncthreads();
    const int wv = t >> 6, lane = t & 63;
    const int row = (bid - 13)*4 + wv;     // 0..39, active < 37
    if (row < 37){
      float v, sgn;
      if (row < 32){ v = W0a[row*64 + lane]; sgn = 1.f; }
      else {
        const int r = row - 32;
        float b = bp0[r*64 + lane];
        float ssq = b*b;
        #pragma unroll
        for (int d = 1; d < 64; d <<= 1) ssq += __shfl_xor(ssq, d);
        float fc = radial_factor(ssq, 1.0f, 1.0f);
        v = b*fc;
        bown0[r*64 + lane] = v;
        sgn = -1.f;
      }
      float acc = v;
      for (int k = 1; k <= 12; ++k){
        const float coef = sgn/(float)k;
        float nv = 0.f;
        #pragma unroll
        for (int m = 0; m < 64; m += 4){
          f32x4 s4 = *(const f32x4*)&ST[lane][m];
          nv += __int_as_float(__builtin_amdgcn_readlane(__float_as_int(v), m+0))*s4[0];
          nv += __int_as_float(__builtin_amdgcn_readlane(__float_as_int(v), m+1))*s4[1];
          nv += __int_as_float(__builtin_amdgcn_readlane(__float_as_int(v), m+2))*s4[2];
          nv += __int_as_float(__builtin_amdgcn_readlane(__float_as_int(v), m+3))*s4[3];
        }
        nv *= coef;
        v = nv; acc += nv;
      }
      if (row < 32) W0aE[row*64 + lane] = acc;
      else          brot0[(row-32)*64 + lane] = acc;
    }
  }
}

// ============ kernel 1: GEMM, depth-3 counted-vmcnt pipeline (unchanged from R9) ============
__global__ __launch_bounds__(256, 4) void gemm_v(
    const float* __restrict__ x,
    const unsigned short* __restrict__ Wcs,
    const float* __restrict__ bcomb,
    const float* __restrict__ zerog,
    float* __restrict__ v)
{
  __shared__ __align__(16) char smem[36864];
  char* xsB  = smem;           // [3][8192]
  char* wcsB = smem + 24576;   // [3][4096]

  const int tid  = threadIdx.x;
  const int lane = tid & 63;
  const int w    = tid >> 6;
  const int wr   = w >> 1, wc = w & 1;
  const int lr   = lane & 15, lkg = lane >> 4;
  const size_t rowBase = (size_t)blockIdx.x * 64;

  const int row8 = lane >> 3;
  const int qs   = lane & 7;
  const int qoff = qs ^ row8;
  const float* xsrcA = x + (rowBase + (size_t)(8*w     + row8))*784 + qoff*4;
  const float* xsrcB = x + (rowBase + (size_t)(8*(w+4) + row8))*784 + qoff*4;
  const unsigned short* wsrc = Wcs + (16*w + (lane>>2))*32 + (lane&3)*8;

  const int rA0 = wr*32 + lr;
  const int sA0 = (2*lkg)     ^ (lr & 7);
  const int sA1 = (2*lkg + 1) ^ (lr & 7);
  const int offA00 = rA0*128 + sA0*16;
  const int offA01 = rA0*128 + sA1*16;
  const int rB0 = wc*32 + lr;
  const int sB  = lkg ^ ((rB0 >> 1) & 3);
  const int offB0 = rB0*64 + sB*16;

#define STAGE(slab, buf) do{                                                   \
    const int ks_ = (slab)*32;                                                 \
    char* xd_ = xsB  + (buf)*8192;                                             \
    char* wd_ = wcsB + (buf)*4096;                                             \
    const float* sa_ = (ks_ + qoff*4 < 784) ? (xsrcA + ks_) : zerog;           \
    const float* sb_ = (ks_ + qoff*4 < 784) ? (xsrcB + ks_) : zerog;           \
    gload_lds16(sa_, xd_ + w*1024);                                            \
    gload_lds16(sb_, xd_ + (w+4)*1024);                                        \
    gload_lds16(wsrc + (size_t)(slab)*2048, wd_ + w*1024);                     \
  }while(0)

  f32x4 acc00 = {}, acc01 = {}, acc10 = {}, acc11 = {};

#define BODY(tt, VMSTR) do{                                                    \
    asm volatile("s_waitcnt " VMSTR ::: "memory");                             \
    __builtin_amdgcn_sched_barrier(0);                                         \
    __builtin_amdgcn_s_barrier();                                              \
    const int cur_ = (tt) % 3;                                                 \
    const char* xb_ = xsB  + cur_*8192;                                        \
    const char* wb_ = wcsB + cur_*4096;                                        \
    f32x4 a00_ = *(const f32x4*)(xb_ + offA00);                                \
    f32x4 a01_ = *(const f32x4*)(xb_ + offA01);                                \
    f32x4 a10_ = *(const f32x4*)(xb_ + offA00 + 2048);                         \
    f32x4 a11_ = *(const f32x4*)(xb_ + offA01 + 2048);                         \
    bf16x8 b0_ = *(const bf16x8*)(wb_ + offB0);                                \
    bf16x8 b1_ = *(const bf16x8*)(wb_ + offB0 + 1024);                         \
    u32x4 pk0_ = { f2bf_pk(a00_[0],a00_[1]), f2bf_pk(a00_[2],a00_[3]),         \
                   f2bf_pk(a01_[0],a01_[1]), f2bf_pk(a01_[2],a01_[3]) };       \
    u32x4 pk1_ = { f2bf_pk(a10_[0],a10_[1]), f2bf_pk(a10_[2],a10_[3]),         \
                   f2bf_pk(a11_[0],a11_[1]), f2bf_pk(a11_[2],a11_[3]) };       \
    bf16x8 af0_ = __builtin_bit_cast(bf16x8, pk0_);                            \
    bf16x8 af1_ = __builtin_bit_cast(bf16x8, pk1_);                            \
    acc00 = __builtin_amdgcn_mfma_f32_16x16x32_bf16(af0_, b0_, acc00, 0,0,0);  \
    acc01 = __builtin_amdgcn_mfma_f32_16x16x32_bf16(af0_, b1_, acc01, 0,0,0);  \
    acc10 = __builtin_amdgcn_mfma_f32_16x16x32_bf16(af1_, b0_, acc10, 0,0,0);  \
    acc11 = __builtin_amdgcn_mfma_f32_16x16x32_bf16(af1_, b1_, acc11, 0,0,0);  \
    asm volatile("s_waitcnt lgkmcnt(0)" ::: "memory");                         \
    __builtin_amdgcn_sched_barrier(0);                                         \
    __builtin_amdgcn_s_barrier();                                              \
    if ((tt) + 3 < 25) STAGE((tt)+3, cur_);                                    \
  }while(0)

  STAGE(0, 0); STAGE(1, 1); STAGE(2, 2);

  for (int t = 0; t < 23; ++t)
    BODY(t, "vmcnt(6)");
  BODY(23, "vmcnt(3)");
  BODY(24, "vmcnt(0)");

#undef BODY
#undef STAGE

  {
    f32x4 accA[2][2] = { {acc00, acc01}, {acc10, acc11} };
    #pragma unroll
    for (int fj = 0; fj < 2; ++fj){
      const int col = wc*32 + fj*16 + lr;
      const float bc = bcomb[col];
      #pragma unroll
      for (int fi = 0; fi < 2; ++fi){
        const int r0 = wr*32 + fi*16 + lkg*4;
        #pragma unroll
        for (int j = 0; j < 4; ++j)
          v[(rowBase + (size_t)(r0 + j))*64 + col] = accA[fi][fj][j] + bc;
      }
    }
  }
}

// ============ kernel 2: row phase with integrated small-folds (prep_small absorbed) ============
// smem layout (bytes):
//   0      vlds [64][76]          19456
//   19456  gv   [64][36]           9216   (P0-P1: W0aE_tmp 8192B)
//   28672  union 8192: cW0aT[64][32] (R2) | g1 stride20 @28672 + cW1b @33792 (R4+)
//          (P0-P1: brot0_tmp @33792, 1280B)
//   36864  cmb0 | 37120 cW0b | 37632 cW1aE | 37888 cb0a | 38016 cb0b | 38032 cmb1
//   38048  cb1a | 38112 cb1b | 38240 cbout | 38304 gS[160] | 38944 c1S[20]
//   39040  fac1[3] | 39056 Mq[16] -> 39120
__global__ __launch_bounds__(256, 4) void row_phase(
    const float* __restrict__ vg,
    const float* __restrict__ W0aE, const float* __restrict__ brot0,
    const float* __restrict__ bown0,
    const float* __restrict__ bp1,
    const float* __restrict__ p_quat, const float* __restrict__ q_quat,
    const float* __restrict__ W1a,
    const float* __restrict__ b0a, const float* __restrict__ W0b, const float* __restrict__ b0b,
    const float* __restrict__ b1a, const float* __restrict__ W1b, const float* __restrict__ b1b,
    const float* __restrict__ Wout, const float* __restrict__ bout,
    float* __restrict__ out)
{
  __shared__ __align__(16) char smem[39168];
  float* vlds   = (float*)smem;                    // stride 76
  float* gv     = (float*)(smem + 19456);          // stride 36; P0: W0aE_tmp
  float* W0aE_t = (float*)(smem + 19456);          // alias
  float* cW0aTS = (float*)(smem + 28672);          // [64][32] (R2)
  float* g1     = (float*)(smem + 28672);          // stride 20 (R4+)
  float* cW1bS  = (float*)(smem + 33792);          // [32][16] (R5); P0-P1: brot0_tmp
  float* brot_t = (float*)(smem + 33792);          // alias
  float* cmb0S  = (float*)(smem + 36864);
  float* cW0bS  = (float*)(smem + 37120);
  float* cW1aES = (float*)(smem + 37632);
  float* cb0aS  = (float*)(smem + 37888);
  float* cb0bS  = (float*)(smem + 38016);
  float* cmb1S  = (float*)(smem + 38032);
  float* cb1aS  = (float*)(smem + 38048);
  float* cb1bS  = (float*)(smem + 38112);
  float* cboutS = (float*)(smem + 38240);
  float* gS     = (float*)(smem + 38304);          // [5][32]
  float* c1S    = (float*)(smem + 38944);          // [5][4]
  float* fac1S  = (float*)(smem + 39040);          // [3]
  float* MqS    = (float*)(smem + 39056);          // [4][4]

  const int tid = threadIdx.x;
  const size_t rowBase = (size_t)blockIdx.x * 64;

  // ---- P0: bulk loads + scalar folds ----
  for (int i = tid; i < 1024; i += 256){
    const int r = i >> 4, seg = i & 15;
    *(f32x4*)&vlds[r*76 + seg*4] = *(const f32x4*)(vg + (rowBase + (size_t)r)*64 + seg*4);
  }
  for (int i = tid; i < 2048; i += 256) W0aE_t[i] = W0aE[i];
  for (int i = tid; i < 320;  i += 256) brot_t[i] = brot0[i];
  if (tid < 64){
    float s = 0.f;
    #pragma unroll
    for (int r = 0; r < 5; ++r) s += bown0[r*64 + tid];
    cmb0S[tid] = s * 0.2f;
  }
  if (tid < 32)  cb0aS[tid] = b0a[tid];
  if (tid < 128) cW0bS[tid] = W0b[tid];
  if (tid < 4)   cb0bS[tid] = b0b[tid];
  if (tid < 16)  cb1aS[tid] = b1a[tid];
  if (tid < 32)  cb1bS[tid] = b1b[tid];
  if (tid < 10)  cboutS[tid] = bout[tid];
  if (tid >= 192 && tid < 195){
    const int r = tid - 192;
    float ssq = 0.f;
    #pragma unroll
    for (int j = 0; j < 4; ++j){ float b = bp1[r*4+j]; ssq += b*b; }
    fac1S[r] = radial_factor(ssq, 0.8f, 1.0f);
  }
  if (tid == 224){
    float pw=p_quat[0],px=p_quat[1],py=p_quat[2],pz=p_quat[3];
    float n1 = sqrtf(pw*pw+px*px+py*py+pz*pz) + EPSF;
    pw/=n1; px/=n1; py/=n1; pz/=n1;
    float qw=q_quat[0],qx=q_quat[1],qy=q_quat[2],qz=q_quat[3];
    float n2 = sqrtf(qw*qw+qx*qx+qy*qy+qz*qz) + EPSF;
    qw/=n2; qx/=n2; qy/=n2; qz/=n2;
    float Lp[4][4] = {{pw,-px,-py,-pz},{px,pw,-pz,py},{py,pz,pw,-px},{pz,-py,px,pw}};
    float Rq[4][4] = {{qw,-qx,-qy,-qz},{qx,qw,qz,-qy},{qy,-qz,qw,qx},{qz,qy,-qx,qw}};
    #pragma unroll
    for (int i = 0; i < 4; ++i)
      #pragma unroll
      for (int k = 0; k < 4; ++k){
        float s = 0.f;
        #pragma unroll
        for (int m = 0; m < 4; ++m) s += Rq[i][m]*Lp[m][k];
        MqS[i*4+k] = s;
      }
  }
  __syncthreads();

  // ---- P1: transpose W0aE -> cW0aT ; g = gelu(b0a + brot0 @ W0aE^T) ; R1 radial ----
  for (int i = tid; i < 2048; i += 256)
    cW0aTS[(i & 63)*32 + (i >> 6)] = W0aE_t[i];
  if (tid < 160){
    const int r = tid >> 5, o = tid & 31;
    float s = cb0aS[o];
    for (int k = 0; k < 64; k += 4){
      f32x4 bb = *(const f32x4*)&brot_t[r*64 + k];
      f32x4 ww = *(const f32x4*)&W0aE_t[o*64 + k];
      s += bb[0]*ww[0] + bb[1]*ww[1] + bb[2]*ww[2] + bb[3]*ww[3];
    }
    gS[r*32 + o] = gelu_f(s);
  }
  const int row = tid >> 2, p4 = tid & 3;
  {
    f32x4 rv[4];
    float* vptr = &vlds[row*76 + p4*16];
    #pragma unroll
    for (int i = 0; i < 4; ++i) rv[i] = ((const f32x4*)vptr)[i];
    float ssq = 0.f;
    #pragma unroll
    for (int i = 0; i < 4; ++i)
      ssq += rv[i][0]*rv[i][0] + rv[i][1]*rv[i][1] + rv[i][2]*rv[i][2] + rv[i][3]*rv[i][3];
    ssq += __shfl_xor(ssq, 1); ssq += __shfl_xor(ssq, 2);
    const float fac = radial_factor(ssq, 1.0f, 1.0f);
    #pragma unroll
    for (int i = 0; i < 4; ++i){ rv[i] *= fac; ((f32x4*)vptr)[i] = rv[i]; }
  }
  __syncthreads();

  // ---- P2: R2 (all threads) + c1 (t<20) + W1aE (t in [64,128)) ----
  {
    const int og = p4;
    float a0o[8];
    #pragma unroll
    for (int j = 0; j < 8; ++j) a0o[j] = cb0aS[og*8 + j];
    #pragma unroll 4
    for (int k = 0; k < 64; k += 4){
      f32x4 vtv = *(const f32x4*)&vlds[row*76 + k];
      f32x4 mm  = *(const f32x4*)&cmb0S[k];
      #pragma unroll
      for (int u = 0; u < 4; ++u){
        const float vc = 2.f*vtv[u] - mm[u];
        const f32x4* wp = (const f32x4*)&cW0aTS[(k+u)*32 + og*8];
        f32x4 w0 = wp[0], w1 = wp[1];
        #pragma unroll
        for (int j = 0; j < 4; ++j){ a0o[j] += w0[j]*vc; a0o[4+j] += w1[j]*vc; }
      }
    }
    #pragma unroll
    for (int j = 0; j < 8; ++j) gv[row*36 + og*8 + j] = gelu_f(a0o[j]);
  }
  if (tid < 20){
    const int r = tid >> 2, o = tid & 3;
    float s = cb0bS[o];
    for (int k = 0; k < 32; ++k) s += gS[r*32+k]*cW0bS[o*32+k];
    c1S[r*4 + o] = s;
  }
  if (tid >= 64 && tid < 128){
    const int i = tid - 64, o = i >> 2, kq = i & 3;
    float s = 0.f;
    #pragma unroll
    for (int j = 0; j < 4; ++j) s += W1a[o*4+j]*MqS[j*4+kq];
    cW1aES[o*4+kq] = s;
  }
  __syncthreads();

  // ---- P3a: mb1 ----
  if (tid < 4){
    float s = 0.f;
    #pragma unroll
    for (int r = 0; r < 3; ++r) s += bp1[r*4+tid]*fac1S[r];
    #pragma unroll
    for (int r = 0; r < 5; ++r) s += c1S[r*4+tid];
    cmb1S[tid] = s * 0.125f;
  }
  __syncthreads();

  // ---- R3 ----
  {
    const int o1 = p4;
    float a1 = cb0bS[o1];
    #pragma unroll
    for (int k = 0; k < 32; k += 4){
      f32x4 gg = *(const f32x4*)&gv[row*36 + k];
      f32x4 ww = *(const f32x4*)&cW0bS[o1*32 + k];
      a1 += gg[0]*ww[0] + gg[1]*ww[1] + gg[2]*ww[2] + gg[3]*ww[3];
    }
    float ss1 = a1*a1;
    ss1 += __shfl_xor(ss1, 1); ss1 += __shfl_xor(ss1, 2);
    const float f1v = radial_factor(ss1, 0.8f, 0.8f);
    const float vt1 = a1*f1v;
    vlds[row*76 + 64 + o1] = vt1;
    vlds[row*76 + 68 + o1] = 2.f*vt1 - cmb1S[o1];
  }
  __syncthreads();

  // ---- R4 (+ stage cW1b) ----
  for (int i = tid; i < 512; i += 256) cW1bS[i] = W1b[i];
  {
    const f32x4 vc1 = *(const f32x4*)&vlds[row*76 + 68];
    #pragma unroll
    for (int j = 0; j < 4; ++j){
      const int o = p4*4 + j;
      float s1 = cb1aS[o] + cW1aES[o*4+0]*vc1[0] + cW1aES[o*4+1]*vc1[1]
                          + cW1aES[o*4+2]*vc1[2] + cW1aES[o*4+3]*vc1[3];
      g1[row*20 + o] = gelu_f(s1);
    }
  }
  __syncthreads();

  // ---- R5 ----
  {
    float v2[8]; float ss2 = 0.f;
    #pragma unroll
    for (int j = 0; j < 8; ++j){
      const int o = p4*8 + j;
      float s = cb1bS[o];
      #pragma unroll
      for (int k = 0; k < 16; k += 4){
        f32x4 gg = *(const f32x4*)&g1[row*20 + k];
        f32x4 ww = *(const f32x4*)&cW1bS[o*16 + k];
        s += gg[0]*ww[0] + gg[1]*ww[1] + gg[2]*ww[2] + gg[3]*ww[3];
      }
      v2[j] = s; ss2 += s*s;
    }
    ss2 += __shfl_xor(ss2, 1); ss2 += __shfl_xor(ss2, 2);
    const float f2v = radial_factor(ss2, 1.2f, 0.6f);
    #pragma unroll
    for (int j = 0; j < 8; ++j) gv[row*36 + p4*8 + j] = v2[j]*f2v;
  }
  __syncthreads();

  // ---- R6 ----
  for (int idx = tid; idx < 640; idx += 256){
    const int r6 = idx/10, o = idx - r6*10;
    float s = cboutS[o];
    const float* wrow = Wout + o*100;
    const float* vrow = &vlds[r6*76];
    #pragma unroll 4
    for (int k = 0; k < 68; k += 4){
      f32x4 a = *(const f32x4*)(vrow + k);
      f32x4 b = *(const f32x4*)(wrow + k);
      s += a[0]*b[0] + a[1]*b[1] + a[2]*b[2] + a[3]*b[3];
    }
    const float* v2row = &gv[r6*36];
    #pragma unroll 4
    for (int k = 0; k < 32; k += 4){
      f32x4 a = *(const f32x4*)(v2row + k);
      f32x4 b = *(const f32x4*)(wrow + 68 + k);
      s += a[0]*b[0] + a[1]*b[1] + a[2]*b[2] + a[3]*b[3];
    }
    out[(rowBase + (size_t)r6)*10 + o] = s;
  }
}

extern "C" void kernel_launch(void* const* d_in, const int* in_sizes, int n_in,
                              void* d_out, int out_size, void* d_ws, size_t ws_size,
                              hipStream_t stream)
{
  (void)n_in; (void)out_size; (void)ws_size;
  const float* x      = (const float*)d_in[0];
  const float* W_in   = (const float*)d_in[1];
  const float* b_in   = (const float*)d_in[2];
  const float* W_tan  = (const float*)d_in[3];
  const float* b_tan  = (const float*)d_in[4];
  const float* bp0    = (const float*)d_in[5];
  const float* bp1    = (const float*)d_in[6];
  /* bp2 = d_in[7] — dead in reference */
  const float* A_rot  = (const float*)d_in[8];
  const float* p_quat = (const float*)d_in[9];
  const float* q_quat = (const float*)d_in[10];
  const float* W0a    = (const float*)d_in[11];
  const float* b0a    = (const float*)d_in[12];
  const float* W0b    = (const float*)d_in[13];
  const float* b0b    = (const float*)d_in[14];
  const float* W1a    = (const float*)d_in[15];
  const float* b1a    = (const float*)d_in[16];
  const float* W1b    = (const float*)d_in[17];
  const float* b1b    = (const float*)d_in[18];
  const float* W_out  = (const float*)d_in[19];
  const float* b_out  = (const float*)d_in[20];

  char* ws = (char*)d_ws;
  unsigned short* Wcs = (unsigned short*)(ws + WS_WC);
  float* bcomb = (float*)(ws + WS_BCOMB);
  float* W0aE  = (float*)(ws + WS_W0AE);
  float* brot0 = (float*)(ws + WS_BROT0);
  float* bown0 = (float*)(ws + WS_BOWN0);
  float* zerog = (float*)(ws + WS_ZERO);
  float* vbuf  = (float*)(ws + WS_V);

  const int Brows = in_sizes[0] / 784;
  const int nblk  = Brows / 64;

  prep_a<<<23, 256, 0, stream>>>(W_in, b_in, W_tan, b_tan, A_rot, W0a, bp0,
                                 Wcs, bcomb, W0aE, brot0, bown0, zerog);
  gemm_v<<<nblk, 256, 0, stream>>>(x, Wcs, bcomb, zerog, vbuf);
  row_phase<<<nblk, 256, 0, stream>>>(vbuf, W0aE, brot0, bown0, bp1,
                                      p_quat, q_quat, W1a,
                                      b0a, W0b, b0b, b1a, W1b, b1b,
                                      W_out, b_out, (float*)d_out);
}

// Round 12
// 79.387 us; speedup vs baseline: 1.2442x; 1.1888x over previous
//
#include <hip/hip_runtime.h>
#include <hip/hip_bf16.h>

typedef __attribute__((ext_vector_type(4))) float f32x4;
typedef __attribute__((ext_vector_type(2))) unsigned int u32x2;
typedef __attribute__((ext_vector_type(4))) unsigned int u32x4;
typedef __attribute__((ext_vector_type(8))) short bf16x8;

#define EPSF 1e-7f

__device__ __forceinline__ float radial_factor(float sumsq, float c, float s){
  float sc = sqrtf(c);
  float nv = sqrtf(sumsq);
  float nu = fmaxf(s*nv, EPSF);
  float th = tanhf(sc*nu);
  float r1 = th/sc;
  float maxn = (1.0f - 1e-5f)/sc;
  float r2 = fminf(r1, maxn);
  float n1 = fmaxf(r2, EPSF);
  float a  = fminf(sc*n1, 1.0f - 1e-7f);
  float r3 = 0.5f*logf((1.0f + a)/(1.0f - a));
  return r3*r2/(sc*n1*nu);
}

__device__ __forceinline__ float gelu_f(float x){
  return 0.5f*x*(1.0f + erff(x*0.70710678118654752f));
}

__device__ __forceinline__ unsigned f2bf1(float f){
  unsigned u = __float_as_uint(f);
  return (u + 0x7FFFu + ((u>>16)&1u)) >> 16;
}
__device__ __forceinline__ unsigned f2bf_pk(float lo, float hi){
  unsigned ul = f2bf1(lo);
  unsigned uh = __float_as_uint(hi);
  uh = (uh + 0x7FFFu + ((uh>>16)&1u)) & 0xFFFF0000u;
  return ul | uh;
}

__device__ __forceinline__ void gload_lds16(const void* g, void* l){
  __builtin_amdgcn_global_load_lds((const __attribute__((address_space(1))) unsigned int*)g,
                                   (__attribute__((address_space(3))) unsigned int*)l,
                                   16, 0, 0);
}

// ---------------- workspace layout (bytes) ----------------
#define WS_WC     0          // bf16 25*2048 elts (swizzled slabs)
#define WS_BCOMB  204800     // f32 [64]
#define WS_W0AE   205056     // f32 [32][64]
#define WS_BROT0  213248     // f32 [5][64]
#define WS_BOWN0  214528     // f32 [5][64]
#define WS_W0AT   215808     // f32 [64][32]
#define WS_MB0    224000     // f32 [64]
#define WS_MB1    224256     // f32 [4]
#define WS_W1AE   224272     // f32 [16][4]
#define WS_ZERO   224528     // f32 [16] zeros

// ============ prep A: blocks 0..12 = W_comb chunks (LDS-tiled); 13..22 = exp rows ============
__global__ __launch_bounds__(256) void prep_a(
    const float* __restrict__ W_in, const float* __restrict__ b_in,
    const float* __restrict__ W_tan, const float* __restrict__ b_tan,
    const float* __restrict__ A_rot, const float* __restrict__ W0a,
    const float* __restrict__ bp0,
    unsigned short* __restrict__ Wc, float* __restrict__ bcomb,
    float* __restrict__ W0aE, float* __restrict__ brot0, float* __restrict__ bown0,
    float* __restrict__ zerog)
{
  __shared__ __align__(16) float Wt[64][132];
  __shared__ __align__(16) float Wi[128][68];
  __shared__ float bin[128];
  __shared__ __align__(16) float Al[64][68];
  __shared__ __align__(16) float ST[64][68];
  const int bid = blockIdx.x, t = threadIdx.x;

  if (bid < 13){
    const int c = bid;
    for (int i = t; i < 2048; i += 256){
      const int n = i >> 5, s4 = i & 31;
      *(f32x4*)&Wt[n][s4*4] = *(const f32x4*)(W_tan + n*128 + s4*4);
    }
    for (int i = t; i < 2048; i += 256){
      const int j = i >> 4, s4 = i & 15;
      const int col = c*64 + s4*4;
      f32x4 v = {0.f,0.f,0.f,0.f};
      if (col < 784) v = *(const f32x4*)(W_in + j*784 + col);
      *(f32x4*)&Wi[j][s4*4] = v;
    }
    if (c == 0 && t < 128) bin[t] = b_in[t];
    __syncthreads();

    const int q  = t & 15;
    const int nb = t >> 4;
    #pragma unroll
    for (int i = 0; i < 4; ++i){
      const int n = nb*4 + i;
      f32x4 acc = {0.f,0.f,0.f,0.f};
      #pragma unroll 4
      for (int j = 0; j < 128; ++j)
        acc += Wt[n][j] * *(const f32x4*)&Wi[j][q*4];
      const int k4 = c*64 + q*4;
      if (k4 < 800){
        u32x2 st = { f2bf_pk(acc[0], acc[1]), f2bf_pk(acc[2], acc[3]) };
        const int tsl = k4 >> 5;
        const int qq  = (k4 >> 3) & 3;
        const int qp  = qq ^ ((n >> 1) & 3);
        const int idx = tsl*2048 + n*32 + qp*8 + (k4 & 7);
        *(u32x2*)(Wc + idx) = st;
      }
    }
    if (c == 0 && t < 64){
      float s = b_tan[t];
      for (int j = 0; j < 128; ++j) s += bin[j]*Wt[t][j];
      bcomb[t] = s;
    }
  } else {
    if (bid == 13 && t < 16) zerog[t] = 0.f;
    for (int m = t; m < 4096; m += 256){
      int r = m >> 6, cc = m & 63;
      Al[r][cc] = A_rot[m];
    }
    __syncthreads();
    for (int m = t; m < 4096; m += 256){
      int r = m >> 6, cc = m & 63;
      ST[r][cc] = Al[cc][r] - Al[r][cc];
    }
    __syncthreads();
    const int wv = t >> 6, lane = t & 63;
    const int row = (bid - 13)*4 + wv;     // 0..39, active < 37
    if (row < 37){
      float v, sgn;
      if (row < 32){ v = W0a[row*64 + lane]; sgn = 1.f; }
      else {
        const int r = row - 32;
        float b = bp0[r*64 + lane];
        float ssq = b*b;
        #pragma unroll
        for (int d = 1; d < 64; d <<= 1) ssq += __shfl_xor(ssq, d);
        float fc = radial_factor(ssq, 1.0f, 1.0f);
        v = b*fc;
        bown0[r*64 + lane] = v;
        sgn = -1.f;
      }
      float acc = v;
      for (int k = 1; k <= 12; ++k){
        const float coef = sgn/(float)k;
        float nv = 0.f;
        #pragma unroll
        for (int m = 0; m < 64; m += 4){
          f32x4 s4 = *(const f32x4*)&ST[lane][m];
          nv += __int_as_float(__builtin_amdgcn_readlane(__float_as_int(v), m+0))*s4[0];
          nv += __int_as_float(__builtin_amdgcn_readlane(__float_as_int(v), m+1))*s4[1];
          nv += __int_as_float(__builtin_amdgcn_readlane(__float_as_int(v), m+2))*s4[2];
          nv += __int_as_float(__builtin_amdgcn_readlane(__float_as_int(v), m+3))*s4[3];
        }
        nv *= coef;
        v = nv; acc += nv;
      }
      if (row < 32) W0aE[row*64 + lane] = acc;
      else          brot0[(row-32)*64 + lane] = acc;
    }
  }
}

// ============ prep B: small folds, once (1 block x 256) ============
__global__ __launch_bounds__(256) void prep_small(
    const float* __restrict__ bp1,
    const float* __restrict__ p_quat, const float* __restrict__ q_quat,
    const float* __restrict__ b0a, const float* __restrict__ W0b, const float* __restrict__ b0b,
    const float* __restrict__ W1a,
    const float* __restrict__ W0aE, const float* __restrict__ brot0, const float* __restrict__ bown0,
    float* __restrict__ W0aT, float* __restrict__ mb0, float* __restrict__ mb1,
    float* __restrict__ W1aE)
{
  __shared__ float g[5][32];
  __shared__ float c1[5][4];
  __shared__ float fac1[3];
  __shared__ float Mq[4][4];
  const int t = threadIdx.x;

  for (int i = t; i < 2048; i += 256){
    int o = i >> 6, k = i & 63;
    W0aT[k*32 + o] = W0aE[i];
  }
  if (t < 64){
    float s = 0.f;
    for (int r = 0; r < 5; ++r) s += bown0[r*64 + t];
    mb0[t] = s * 0.2f;
  }
  if (t < 160){
    int r = t >> 5, o = t & 31;
    float s = b0a[o];
    for (int k = 0; k < 64; ++k) s += brot0[r*64+k]*W0aE[o*64+k];
    g[r][o] = gelu_f(s);
  }
  if (t >= 192 && t < 195){
    int r = t - 192;
    float ssq = 0.f;
    for (int j = 0; j < 4; ++j){ float b = bp1[r*4+j]; ssq += b*b; }
    fac1[r] = radial_factor(ssq, 0.8f, 1.0f);
  }
  if (t == 224){
    float pw=p_quat[0],px=p_quat[1],py=p_quat[2],pz=p_quat[3];
    float n1 = sqrtf(pw*pw+px*px+py*py+pz*pz) + EPSF;
    pw/=n1; px/=n1; py/=n1; pz/=n1;
    float qw=q_quat[0],qx=q_quat[1],qy=q_quat[2],qz=q_quat[3];
    float n2 = sqrtf(qw*qw+qx*qx+qy*qy+qz*qz) + EPSF;
    qw/=n2; qx/=n2; qy/=n2; qz/=n2;
    float Lp[4][4] = {{pw,-px,-py,-pz},{px,pw,-pz,py},{py,pz,pw,-px},{pz,-py,px,pw}};
    float Rq[4][4] = {{qw,-qx,-qy,-qz},{qx,qw,qz,-qy},{qy,-qz,qw,qx},{qz,qy,-qx,qw}};
    #pragma unroll
    for (int i = 0; i < 4; ++i)
      #pragma unroll
      for (int k = 0; k < 4; ++k){
        float s = 0.f;
        #pragma unroll
        for (int m = 0; m < 4; ++m) s += Rq[i][m]*Lp[m][k];
        Mq[i][k] = s;
      }
  }
  __syncthreads();
  if (t < 20){
    int r = t >> 2, o = t & 3;
    float s = b0b[o];
    for (int k = 0; k < 32; ++k) s += g[r][k]*W0b[o*32+k];
    c1[r][o] = s;
  }
  __syncthreads();
  if (t < 4){
    float s = 0.f;
    for (int r = 0; r < 3; ++r) s += bp1[r*4+t]*fac1[r];
    for (int r = 0; r < 5; ++r) s += c1[r][t];
    mb1[t] = s * 0.125f;
  }
  if (t >= 64 && t < 128){
    int i = t - 64, o = i >> 2, kq = i & 3;
    float s = 0.f;
    #pragma unroll
    for (int j = 0; j < 4; ++j) s += W1a[o*4+j]*Mq[j][kq];
    W1aE[o*4+kq] = s;
  }
}

// ============ mega: counted-vmcnt GEMM -> row phase, one kernel, 38.3KB LDS (4 blk/CU) ============
// LDS union (bytes):
//   GEMM phase: xsB @0 [3][8192]=24576 | wcsB @24576 [3][4096]=12288 -> 36864
//   Row phase : vlds @0 [64][76]=19456 | gv @19456 [64][36]=9216 -> 28672
//               cW0aT @28672 [64][32]=8192 (R2) | g1 @28672 [64][20] (R4+) | cW1b @33792 (R5)
//   consts (disjoint, staged at start): 36864..38304
__global__ __launch_bounds__(256, 4) void mega_fused(
    const float* __restrict__ x,
    const unsigned short* __restrict__ Wcs,
    const float* __restrict__ bcomb,
    const float* __restrict__ zerog,
    const float* __restrict__ W0aT,
    const float* __restrict__ mb0g, const float* __restrict__ mb1g,
    const float* __restrict__ W1aEg,
    const float* __restrict__ b0a, const float* __restrict__ W0b, const float* __restrict__ b0b,
    const float* __restrict__ b1a, const float* __restrict__ W1b, const float* __restrict__ b1b,
    const float* __restrict__ Wout, const float* __restrict__ bout,
    float* __restrict__ out)
{
  __shared__ __align__(16) char smem[38304];
  char* xsB    = smem;                       // [3][8192]
  char* wcsB   = smem + 24576;               // [3][4096]
  float* vlds  = (float*)smem;               // stride 76
  float* gv    = (float*)(smem + 19456);     // stride 36
  float* cW0aTS= (float*)(smem + 28672);     // [64][32] (R2)
  float* g1    = (float*)(smem + 28672);     // stride 20 (R4+)
  float* cW1bS = (float*)(smem + 33792);     // [32][16] (R5)
  float* cmb0S  = (float*)(smem + 36864);
  float* cW0bS  = (float*)(smem + 37120);
  float* cW1aES = (float*)(smem + 37632);
  float* cb0aS  = (float*)(smem + 37888);
  float* cb0bS  = (float*)(smem + 38016);
  float* cmb1S  = (float*)(smem + 38032);
  float* cb1aS  = (float*)(smem + 38048);
  float* cb1bS  = (float*)(smem + 38112);
  float* cboutS = (float*)(smem + 38240);

  const int tid  = threadIdx.x;
  const int lane = tid & 63;
  const int w    = tid >> 6;
  const int wr   = w >> 1, wc = w & 1;
  const int lr   = lane & 15, lkg = lane >> 4;
  const size_t rowBase = (size_t)blockIdx.x * 64;

  // ---- stage small consts (region disjoint from GEMM buffers) ----
  if (tid < 64)  cmb0S[tid] = mb0g[tid];
  if (tid < 128) cW0bS[tid] = W0b[tid];
  if (tid < 64)  cW1aES[tid] = W1aEg[tid];
  if (tid < 32)  cb0aS[tid] = b0a[tid];
  if (tid < 4)   { cb0bS[tid] = b0b[tid]; cmb1S[tid] = mb1g[tid]; }
  if (tid < 16)  cb1aS[tid] = b1a[tid];
  if (tid < 32)  cb1bS[tid] = b1b[tid];
  if (tid < 10)  cboutS[tid] = bout[tid];

  // ---- GEMM (counted-vmcnt depth-3 pipeline, R9 core) ----
  const int row8 = lane >> 3;
  const int qs   = lane & 7;
  const int qoff = qs ^ row8;
  const float* xsrcA = x + (rowBase + (size_t)(8*w     + row8))*784 + qoff*4;
  const float* xsrcB = x + (rowBase + (size_t)(8*(w+4) + row8))*784 + qoff*4;
  const unsigned short* wsrc = Wcs + (16*w + (lane>>2))*32 + (lane&3)*8;

  const int rA0 = wr*32 + lr;
  const int sA0 = (2*lkg)     ^ (lr & 7);
  const int sA1 = (2*lkg + 1) ^ (lr & 7);
  const int offA00 = rA0*128 + sA0*16;
  const int offA01 = rA0*128 + sA1*16;
  const int rB0 = wc*32 + lr;
  const int sB  = lkg ^ ((rB0 >> 1) & 3);
  const int offB0 = rB0*64 + sB*16;

#define STAGE(slab, buf) do{                                                   \
    const int ks_ = (slab)*32;                                                 \
    char* xd_ = xsB  + (buf)*8192;                                             \
    char* wd_ = wcsB + (buf)*4096;                                             \
    const float* sa_ = (ks_ + qoff*4 < 784) ? (xsrcA + ks_) : zerog;           \
    const float* sb_ = (ks_ + qoff*4 < 784) ? (xsrcB + ks_) : zerog;           \
    gload_lds16(sa_, xd_ + w*1024);                                            \
    gload_lds16(sb_, xd_ + (w+4)*1024);                                        \
    gload_lds16(wsrc + (size_t)(slab)*2048, wd_ + w*1024);                     \
  }while(0)

  f32x4 acc00 = {}, acc01 = {}, acc10 = {}, acc11 = {};

#define BODY(tt, VMSTR) do{                                                    \
    asm volatile("s_waitcnt " VMSTR ::: "memory");                             \
    __builtin_amdgcn_sched_barrier(0);                                         \
    __builtin_amdgcn_s_barrier();                                              \
    const int cur_ = (tt) % 3;                                                 \
    const char* xb_ = xsB  + cur_*8192;                                        \
    const char* wb_ = wcsB + cur_*4096;                                        \
    f32x4 a00_ = *(const f32x4*)(xb_ + offA00);                                \
    f32x4 a01_ = *(const f32x4*)(xb_ + offA01);                                \
    f32x4 a10_ = *(const f32x4*)(xb_ + offA00 + 2048);                         \
    f32x4 a11_ = *(const f32x4*)(xb_ + offA01 + 2048);                         \
    bf16x8 b0_ = *(const bf16x8*)(wb_ + offB0);                                \
    bf16x8 b1_ = *(const bf16x8*)(wb_ + offB0 + 1024);                         \
    u32x4 pk0_ = { f2bf_pk(a00_[0],a00_[1]), f2bf_pk(a00_[2],a00_[3]),         \
                   f2bf_pk(a01_[0],a01_[1]), f2bf_pk(a01_[2],a01_[3]) };       \
    u32x4 pk1_ = { f2bf_pk(a10_[0],a10_[1]), f2bf_pk(a10_[2],a10_[3]),         \
                   f2bf_pk(a11_[0],a11_[1]), f2bf_pk(a11_[2],a11_[3]) };       \
    bf16x8 af0_ = __builtin_bit_cast(bf16x8, pk0_);                            \
    bf16x8 af1_ = __builtin_bit_cast(bf16x8, pk1_);                            \
    acc00 = __builtin_amdgcn_mfma_f32_16x16x32_bf16(af0_, b0_, acc00, 0,0,0);  \
    acc01 = __builtin_amdgcn_mfma_f32_16x16x32_bf16(af0_, b1_, acc01, 0,0,0);  \
    acc10 = __builtin_amdgcn_mfma_f32_16x16x32_bf16(af1_, b0_, acc10, 0,0,0);  \
    acc11 = __builtin_amdgcn_mfma_f32_16x16x32_bf16(af1_, b1_, acc11, 0,0,0);  \
    asm volatile("s_waitcnt lgkmcnt(0)" ::: "memory");                         \
    __builtin_amdgcn_sched_barrier(0);                                         \
    __builtin_amdgcn_s_barrier();                                              \
    if ((tt) + 3 < 25) STAGE((tt)+3, cur_);                                    \
  }while(0)

  STAGE(0, 0); STAGE(1, 1); STAGE(2, 2);

  for (int t = 0; t < 23; ++t)
    BODY(t, "vmcnt(6)");
  BODY(23, "vmcnt(3)");
  BODY(24, "vmcnt(0)");

#undef BODY
#undef STAGE

  // ---- epilogue: acc -> vlds (GEMM buffers dead after final barrier) ----
  {
    f32x4 accA[2][2] = { {acc00, acc01}, {acc10, acc11} };
    #pragma unroll
    for (int fj = 0; fj < 2; ++fj){
      const int col = wc*32 + fj*16 + lr;
      const float bc = bcomb[col];
      #pragma unroll
      for (int fi = 0; fi < 2; ++fi){
        const int r0 = wr*32 + fi*16 + lkg*4;
        #pragma unroll
        for (int j = 0; j < 4; ++j)
          vlds[(r0 + j)*76 + col] = accA[fi][fj][j] + bc;
      }
    }
  }
  for (int i = tid; i < 2048; i += 256) cW0aTS[i] = W0aT[i];
  __syncthreads();

  const int row = tid >> 2, p4 = tid & 3;

  // R1: v_tan0 = radial(v)  (in place)
  {
    f32x4 rv[4];
    float* vptr = &vlds[row*76 + p4*16];
    #pragma unroll
    for (int i = 0; i < 4; ++i) rv[i] = ((const f32x4*)vptr)[i];
    float ssq = 0.f;
    #pragma unroll
    for (int i = 0; i < 4; ++i)
      ssq += rv[i][0]*rv[i][0] + rv[i][1]*rv[i][1] + rv[i][2]*rv[i][2] + rv[i][3]*rv[i][3];
    ssq += __shfl_xor(ssq, 1); ssq += __shfl_xor(ssq, 2);
    const float fac = radial_factor(ssq, 1.0f, 1.0f);
    #pragma unroll
    for (int i = 0; i < 4; ++i){ rv[i] *= fac; ((f32x4*)vptr)[i] = rv[i]; }
  }
  __syncthreads();

  // R2: a0 = W0aE @ (2*vt0 - mb0) + b0a ; g0 = gelu(a0)
  {
    const int og = p4;
    float a0o[8];
    #pragma unroll
    for (int j = 0; j < 8; ++j) a0o[j] = cb0aS[og*8 + j];
    #pragma unroll 4
    for (int k = 0; k < 64; k += 4){
      f32x4 vtv = *(const f32x4*)&vlds[row*76 + k];
      f32x4 mm  = *(const f32x4*)&cmb0S[k];
      #pragma unroll
      for (int u = 0; u < 4; ++u){
        const float vc = 2.f*vtv[u] - mm[u];
        const f32x4* wp = (const f32x4*)&cW0aTS[(k+u)*32 + og*8];
        f32x4 w0 = wp[0], w1 = wp[1];
        #pragma unroll
        for (int j = 0; j < 4; ++j){ a0o[j] += w0[j]*vc; a0o[4+j] += w1[j]*vc; }
      }
    }
    #pragma unroll
    for (int j = 0; j < 8; ++j) gv[row*36 + og*8 + j] = gelu_f(a0o[j]);
  }
  __syncthreads();

  // R3: v1 = W0b@g0 + b0b; v_tan1, v_comb1
  {
    const int o1 = p4;
    float a1 = cb0bS[o1];
    #pragma unroll
    for (int k = 0; k < 32; k += 4){
      f32x4 gg = *(const f32x4*)&gv[row*36 + k];
      f32x4 ww = *(const f32x4*)&cW0bS[o1*32 + k];
      a1 += gg[0]*ww[0] + gg[1]*ww[1] + gg[2]*ww[2] + gg[3]*ww[3];
    }
    float ss1 = a1*a1;
    ss1 += __shfl_xor(ss1, 1); ss1 += __shfl_xor(ss1, 2);
    const float f1v = radial_factor(ss1, 0.8f, 0.8f);
    const float vt1 = a1*f1v;
    vlds[row*76 + 64 + o1] = vt1;
    vlds[row*76 + 68 + o1] = 2.f*vt1 - cmb1S[o1];
  }
  __syncthreads();

  // R4: a1 = W1aE @ vc1 + b1a ; g1 = gelu   (+ stage cW1b)
  for (int i = tid; i < 512; i += 256) cW1bS[i] = W1b[i];
  {
    const f32x4 vc1 = *(const f32x4*)&vlds[row*76 + 68];
    #pragma unroll
    for (int j = 0; j < 4; ++j){
      const int o = p4*4 + j;
      float s1 = cb1aS[o] + cW1aES[o*4+0]*vc1[0] + cW1aES[o*4+1]*vc1[1]
                          + cW1aES[o*4+2]*vc1[2] + cW1aES[o*4+3]*vc1[3];
      g1[row*20 + o] = gelu_f(s1);
    }
  }
  __syncthreads();

  // R5: v2 = W1b@g1 + b1b; v_tan2 -> gv
  {
    float v2[8]; float ss2 = 0.f;
    #pragma unroll
    for (int j = 0; j < 8; ++j){
      const int o = p4*8 + j;
      float s = cb1bS[o];
      #pragma unroll
      for (int k = 0; k < 16; k += 4){
        f32x4 gg = *(const f32x4*)&g1[row*20 + k];
        f32x4 ww = *(const f32x4*)&cW1bS[o*16 + k];
        s += gg[0]*ww[0] + gg[1]*ww[1] + gg[2]*ww[2] + gg[3]*ww[3];
      }
      v2[j] = s; ss2 += s*s;
    }
    ss2 += __shfl_xor(ss2, 1); ss2 += __shfl_xor(ss2, 2);
    const float f2v = radial_factor(ss2, 1.2f, 0.6f);
    #pragma unroll
    for (int j = 0; j < 8; ++j) gv[row*36 + p4*8 + j] = v2[j]*f2v;
  }
  __syncthreads();

  // R6: out = W_out @ concat(vt0, vt1, vt2) + b_out   (Wout from L2)
  for (int idx = tid; idx < 640; idx += 256){
    const int r6 = idx/10, o = idx - r6*10;
    float s = cboutS[o];
    const float* wrow = Wout + o*100;
    const float* vrow = &vlds[r6*76];
    #pragma unroll 4
    for (int k = 0; k < 68; k += 4){
      f32x4 a = *(const f32x4*)(vrow + k);
      f32x4 b = *(const f32x4*)(wrow + k);
      s += a[0]*b[0] + a[1]*b[1] + a[2]*b[2] + a[3]*b[3];
    }
    const float* v2row = &gv[r6*36];
    #pragma unroll 4
    for (int k = 0; k < 32; k += 4){
      f32x4 a = *(const f32x4*)(v2row + k);
      f32x4 b = *(const f32x4*)(wrow + 68 + k);
      s += a[0]*b[0] + a[1]*b[1] + a[2]*b[2] + a[3]*b[3];
    }
    out[(rowBase + (size_t)r6)*10 + o] = s;
  }
}

extern "C" void kernel_launch(void* const* d_in, const int* in_sizes, int n_in,
                              void* d_out, int out_size, void* d_ws, size_t ws_size,
                              hipStream_t stream)
{
  (void)n_in; (void)out_size; (void)ws_size;
  const float* x      = (const float*)d_in[0];
  const float* W_in   = (const float*)d_in[1];
  const float* b_in   = (const float*)d_in[2];
  const float* W_tan  = (const float*)d_in[3];
  const float* b_tan  = (const float*)d_in[4];
  const float* bp0    = (const float*)d_in[5];
  const float* bp1    = (const float*)d_in[6];
  /* bp2 = d_in[7] — dead in reference */
  const float* A_rot  = (const float*)d_in[8];
  const float* p_quat = (const float*)d_in[9];
  const float* q_quat = (const float*)d_in[10];
  const float* W0a    = (const float*)d_in[11];
  const float* b0a    = (const float*)d_in[12];
  const float* W0b    = (const float*)d_in[13];
  const float* b0b    = (const float*)d_in[14];
  const float* W1a    = (const float*)d_in[15];
  const float* b1a    = (const float*)d_in[16];
  const float* W1b    = (const float*)d_in[17];
  const float* b1b    = (const float*)d_in[18];
  const float* W_out  = (const float*)d_in[19];
  const float* b_out  = (const float*)d_in[20];

  char* ws = (char*)d_ws;
  unsigned short* Wcs = (unsigned short*)(ws + WS_WC);
  float* bcomb = (float*)(ws + WS_BCOMB);
  float* W0aE  = (float*)(ws + WS_W0AE);
  float* brot0 = (float*)(ws + WS_BROT0);
  float* bown0 = (float*)(ws + WS_BOWN0);
  float* W0aT  = (float*)(ws + WS_W0AT);
  float* mb0   = (float*)(ws + WS_MB0);
  float* mb1   = (float*)(ws + WS_MB1);
  float* W1aE  = (float*)(ws + WS_W1AE);
  float* zerog = (float*)(ws + WS_ZERO);

  const int Brows = in_sizes[0] / 784;
  const int nblk  = Brows / 64;

  prep_a<<<23, 256, 0, stream>>>(W_in, b_in, W_tan, b_tan, A_rot, W0a, bp0,
                                 Wcs, bcomb, W0aE, brot0, bown0, zerog);
  prep_small<<<1, 256, 0, stream>>>(bp1, p_quat, q_quat, b0a, W0b, b0b, W1a,
                                    W0aE, brot0, bown0, W0aT, mb0, mb1, W1aE);
  mega_fused<<<nblk, 256, 0, stream>>>(x, Wcs, bcomb, zerog, W0aT, mb0, mb1, W1aE,
                                       b0a, W0b, b0b, b1a, W1b, b1b,
                                       W_out, b_out, (float*)d_out);
}

// Round 13
// 77.879 us; speedup vs baseline: 1.2683x; 1.0194x over previous
//
#include <hip/hip_runtime.h>
#include <hip/hip_bf16.h>

typedef __attribute__((ext_vector_type(4))) float f32x4;
typedef __attribute__((ext_vector_type(2))) unsigned int u32x2;
typedef __attribute__((ext_vector_type(4))) unsigned int u32x4;
typedef __attribute__((ext_vector_type(8))) short bf16x8;

#define EPSF 1e-7f

__device__ __forceinline__ float radial_factor(float sumsq, float c, float s){
  float sc = sqrtf(c);
  float nv = sqrtf(sumsq);
  float nu = fmaxf(s*nv, EPSF);
  float th = tanhf(sc*nu);
  float r1 = th/sc;
  float maxn = (1.0f - 1e-5f)/sc;
  float r2 = fminf(r1, maxn);
  float n1 = fmaxf(r2, EPSF);
  float a  = fminf(sc*n1, 1.0f - 1e-7f);
  float r3 = 0.5f*logf((1.0f + a)/(1.0f - a));
  return r3*r2/(sc*n1*nu);
}

__device__ __forceinline__ float gelu_f(float x){
  return 0.5f*x*(1.0f + erff(x*0.70710678118654752f));
}

__device__ __forceinline__ unsigned f2bf1(float f){
  unsigned u = __float_as_uint(f);
  return (u + 0x7FFFu + ((u>>16)&1u)) >> 16;
}
__device__ __forceinline__ unsigned f2bf_pk(float lo, float hi){
  unsigned ul = f2bf1(lo);
  unsigned uh = __float_as_uint(hi);
  uh = (uh + 0x7FFFu + ((uh>>16)&1u)) & 0xFFFF0000u;
  return ul | uh;
}
// truncation pack (3 VALU ops): low half = lo>>16, high half = hi's high 16
__device__ __forceinline__ unsigned trunc_pk(float lo, float hi){
  return (__float_as_uint(hi) & 0xFFFF0000u) | (__float_as_uint(lo) >> 16);
}

__device__ __forceinline__ void gload_lds16(const void* g, void* l){
  __builtin_amdgcn_global_load_lds((const __attribute__((address_space(1))) unsigned int*)g,
                                   (__attribute__((address_space(3))) unsigned int*)l,
                                   16, 0, 0);
}

// ---------------- workspace layout (bytes) ----------------
#define WS_WC     0          // bf16 25*2048 elts (swizzled slabs)
#define WS_BCOMB  204800     // f32 [64]
#define WS_W0AE   205056     // f32 [32][64]
#define WS_BROT0  213248     // f32 [5][64]
#define WS_BOWN0  214528     // f32 [5][64]
#define WS_W0AT   215808     // f32 [64][32]
#define WS_MB0    224000     // f32 [64]
#define WS_MB1    224256     // f32 [4]
#define WS_W1AE   224272     // f32 [16][4]
#define WS_ZERO   224528     // f32 [16] zeros

// ============ prep A: blocks 0..12 = W_comb chunks (LDS-tiled); 13..22 = exp rows ============
__global__ __launch_bounds__(256) void prep_a(
    const float* __restrict__ W_in, const float* __restrict__ b_in,
    const float* __restrict__ W_tan, const float* __restrict__ b_tan,
    const float* __restrict__ A_rot, const float* __restrict__ W0a,
    const float* __restrict__ bp0,
    unsigned short* __restrict__ Wc, float* __restrict__ bcomb,
    float* __restrict__ W0aE, float* __restrict__ brot0, float* __restrict__ bown0,
    float* __restrict__ zerog)
{
  __shared__ __align__(16) float Wt[64][132];
  __shared__ __align__(16) float Wi[128][68];
  __shared__ float bin[128];
  __shared__ __align__(16) float Al[64][68];
  __shared__ __align__(16) float ST[64][68];
  const int bid = blockIdx.x, t = threadIdx.x;

  if (bid < 13){
    const int c = bid;
    for (int i = t; i < 2048; i += 256){
      const int n = i >> 5, s4 = i & 31;
      *(f32x4*)&Wt[n][s4*4] = *(const f32x4*)(W_tan + n*128 + s4*4);
    }
    for (int i = t; i < 2048; i += 256){
      const int j = i >> 4, s4 = i & 15;
      const int col = c*64 + s4*4;
      f32x4 v = {0.f,0.f,0.f,0.f};
      if (col < 784) v = *(const f32x4*)(W_in + j*784 + col);
      *(f32x4*)&Wi[j][s4*4] = v;
    }
    if (c == 0 && t < 128) bin[t] = b_in[t];
    __syncthreads();

    const int q  = t & 15;
    const int nb = t >> 4;
    #pragma unroll
    for (int i = 0; i < 4; ++i){
      const int n = nb*4 + i;
      f32x4 acc = {0.f,0.f,0.f,0.f};
      #pragma unroll 4
      for (int j = 0; j < 128; ++j)
        acc += Wt[n][j] * *(const f32x4*)&Wi[j][q*4];
      const int k4 = c*64 + q*4;
      if (k4 < 800){
        u32x2 st = { f2bf_pk(acc[0], acc[1]), f2bf_pk(acc[2], acc[3]) };
        const int tsl = k4 >> 5;
        const int qq  = (k4 >> 3) & 3;
        const int qp  = qq ^ ((n >> 1) & 3);
        const int idx = tsl*2048 + n*32 + qp*8 + (k4 & 7);
        *(u32x2*)(Wc + idx) = st;
      }
    }
    if (c == 0 && t < 64){
      float s = b_tan[t];
      for (int j = 0; j < 128; j += 4){
        f32x4 bb = *(const f32x4*)&bin[j];
        f32x4 ww = *(const f32x4*)&Wt[t][j];
        s += bb[0]*ww[0] + bb[1]*ww[1] + bb[2]*ww[2] + bb[3]*ww[3];
      }
      bcomb[t] = s;
    }
  } else {
    if (bid == 13 && t < 16) zerog[t] = 0.f;
    for (int m = t; m < 4096; m += 256){
      int r = m >> 6, cc = m & 63;
      Al[r][cc] = A_rot[m];
    }
    __syncthreads();
    for (int m = t; m < 4096; m += 256){
      int r = m >> 6, cc = m & 63;
      ST[r][cc] = Al[cc][r] - Al[r][cc];
    }
    __syncthreads();
    const int wv = t >> 6, lane = t & 63;
    const int row = (bid - 13)*4 + wv;     // 0..39, active < 37
    if (row < 37){
      float v, sgn;
      if (row < 32){ v = W0a[row*64 + lane]; sgn = 1.f; }
      else {
        const int r = row - 32;
        float b = bp0[r*64 + lane];
        float ssq = b*b;
        #pragma unroll
        for (int d = 1; d < 64; d <<= 1) ssq += __shfl_xor(ssq, d);
        float fc = radial_factor(ssq, 1.0f, 1.0f);
        v = b*fc;
        bown0[r*64 + lane] = v;
        sgn = -1.f;
      }
      float acc = v;
      for (int k = 1; k <= 12; ++k){
        const float coef = sgn/(float)k;
        float nv = 0.f;
        #pragma unroll
        for (int m = 0; m < 64; m += 4){
          f32x4 s4 = *(const f32x4*)&ST[lane][m];
          nv += __int_as_float(__builtin_amdgcn_readlane(__float_as_int(v), m+0))*s4[0];
          nv += __int_as_float(__builtin_amdgcn_readlane(__float_as_int(v), m+1))*s4[1];
          nv += __int_as_float(__builtin_amdgcn_readlane(__float_as_int(v), m+2))*s4[2];
          nv += __int_as_float(__builtin_amdgcn_readlane(__float_as_int(v), m+3))*s4[3];
        }
        nv *= coef;
        v = nv; acc += nv;
      }
      if (row < 32) W0aE[row*64 + lane] = acc;
      else          brot0[(row-32)*64 + lane] = acc;
    }
  }
}

// ============ prep B: small folds, once (1 block x 256), vectorized chains ============
__global__ __launch_bounds__(256) void prep_small(
    const float* __restrict__ bp1,
    const float* __restrict__ p_quat, const float* __restrict__ q_quat,
    const float* __restrict__ b0a, const float* __restrict__ W0b, const float* __restrict__ b0b,
    const float* __restrict__ W1a,
    const float* __restrict__ W0aE, const float* __restrict__ brot0, const float* __restrict__ bown0,
    float* __restrict__ W0aT, float* __restrict__ mb0, float* __restrict__ mb1,
    float* __restrict__ W1aE)
{
  __shared__ float g[5][32];
  __shared__ float c1[5][4];
  __shared__ float fac1[3];
  __shared__ float Mq[4][4];
  const int t = threadIdx.x;

  for (int i = t; i < 2048; i += 256){
    int o = i >> 6, k = i & 63;
    W0aT[k*32 + o] = W0aE[i];
  }
  if (t < 64){
    float s = 0.f;
    #pragma unroll
    for (int r = 0; r < 5; ++r) s += bown0[r*64 + t];
    mb0[t] = s * 0.2f;
  }
  if (t < 160){
    int r = t >> 5, o = t & 31;
    float s = b0a[o];
    #pragma unroll 4
    for (int k = 0; k < 64; k += 4){
      f32x4 bb = *(const f32x4*)(brot0 + r*64 + k);
      f32x4 ww = *(const f32x4*)(W0aE + o*64 + k);
      s += bb[0]*ww[0] + bb[1]*ww[1] + bb[2]*ww[2] + bb[3]*ww[3];
    }
    g[r][o] = gelu_f(s);
  }
  if (t >= 192 && t < 195){
    int r = t - 192;
    float ssq = 0.f;
    #pragma unroll
    for (int j = 0; j < 4; ++j){ float b = bp1[r*4+j]; ssq += b*b; }
    fac1[r] = radial_factor(ssq, 0.8f, 1.0f);
  }
  if (t == 224){
    float pw=p_quat[0],px=p_quat[1],py=p_quat[2],pz=p_quat[3];
    float n1 = sqrtf(pw*pw+px*px+py*py+pz*pz) + EPSF;
    pw/=n1; px/=n1; py/=n1; pz/=n1;
    float qw=q_quat[0],qx=q_quat[1],qy=q_quat[2],qz=q_quat[3];
    float n2 = sqrtf(qw*qw+qx*qx+qy*qy+qz*qz) + EPSF;
    qw/=n2; qx/=n2; qy/=n2; qz/=n2;
    float Lp[4][4] = {{pw,-px,-py,-pz},{px,pw,-pz,py},{py,pz,pw,-px},{pz,-py,px,pw}};
    float Rq[4][4] = {{qw,-qx,-qy,-qz},{qx,qw,qz,-qy},{qy,-qz,qw,qx},{qz,qy,-qx,qw}};
    #pragma unroll
    for (int i = 0; i < 4; ++i)
      #pragma unroll
      for (int k = 0; k < 4; ++k){
        float s = 0.f;
        #pragma unroll
        for (int m = 0; m < 4; ++m) s += Rq[i][m]*Lp[m][k];
        Mq[i][k] = s;
      }
  }
  __syncthreads();
  if (t < 20){
    int r = t >> 2, o = t & 3;
    float s = b0b[o];
    #pragma unroll
    for (int k = 0; k < 32; k += 4){
      f32x4 gg = *(const f32x4*)&g[r][k];
      f32x4 ww = *(const f32x4*)(W0b + o*32 + k);
      s += gg[0]*ww[0] + gg[1]*ww[1] + gg[2]*ww[2] + gg[3]*ww[3];
    }
    c1[r][o] = s;
  }
  __syncthreads();
  if (t < 4){
    float s = 0.f;
    #pragma unroll
    for (int r = 0; r < 3; ++r) s += bp1[r*4+t]*fac1[r];
    #pragma unroll
    for (int r = 0; r < 5; ++r) s += c1[r][t];
    mb1[t] = s * 0.125f;
  }
  if (t >= 64 && t < 128){
    int i = t - 64, o = i >> 2, kq = i & 3;
    float s = 0.f;
    #pragma unroll
    for (int j = 0; j < 4; ++j) s += W1a[o*4+j]*Mq[j][kq];
    W1aE[o*4+kq] = s;
  }
}

// ============ mega: counted-vmcnt GEMM -> row phase, one kernel, 38.3KB LDS (4 blk/CU) ============
__global__ __launch_bounds__(256, 4) void mega_fused(
    const float* __restrict__ x,
    const unsigned short* __restrict__ Wcs,
    const float* __restrict__ bcomb,
    const float* __restrict__ zerog,
    const float* __restrict__ W0aT,
    const float* __restrict__ mb0g, const float* __restrict__ mb1g,
    const float* __restrict__ W1aEg,
    const float* __restrict__ b0a, const float* __restrict__ W0b, const float* __restrict__ b0b,
    const float* __restrict__ b1a, const float* __restrict__ W1b, const float* __restrict__ b1b,
    const float* __restrict__ Wout, const float* __restrict__ bout,
    float* __restrict__ out)
{
  __shared__ __align__(16) char smem[38304];
  char* xsB    = smem;                       // [3][8192]
  char* wcsB   = smem + 24576;               // [3][4096]
  float* vlds  = (float*)smem;               // stride 76
  float* gv    = (float*)(smem + 19456);     // stride 36
  float* cW0aTS= (float*)(smem + 28672);     // [64][32] (R2)
  float* g1    = (float*)(smem + 28672);     // stride 20 (R4+)
  float* cW1bS = (float*)(smem + 33792);     // [32][16] (R5)
  float* cmb0S  = (float*)(smem + 36864);
  float* cW0bS  = (float*)(smem + 37120);
  float* cW1aES = (float*)(smem + 37632);
  float* cb0aS  = (float*)(smem + 37888);
  float* cb0bS  = (float*)(smem + 38016);
  float* cmb1S  = (float*)(smem + 38032);
  float* cb1aS  = (float*)(smem + 38048);
  float* cb1bS  = (float*)(smem + 38112);
  float* cboutS = (float*)(smem + 38240);

  const int tid  = threadIdx.x;
  const int lane = tid & 63;
  const int w    = tid >> 6;
  const int wr   = w >> 1, wc = w & 1;
  const int lr   = lane & 15, lkg = lane >> 4;
  const size_t rowBase = (size_t)blockIdx.x * 64;

  // ---- stage small consts (region disjoint from GEMM buffers) ----
  if (tid < 64)  cmb0S[tid] = mb0g[tid];
  if (tid < 128) cW0bS[tid] = W0b[tid];
  if (tid < 64)  cW1aES[tid] = W1aEg[tid];
  if (tid < 32)  cb0aS[tid] = b0a[tid];
  if (tid < 4)   { cb0bS[tid] = b0b[tid]; cmb1S[tid] = mb1g[tid]; }
  if (tid < 16)  cb1aS[tid] = b1a[tid];
  if (tid < 32)  cb1bS[tid] = b1b[tid];
  if (tid < 10)  cboutS[tid] = bout[tid];

  // ---- GEMM (counted-vmcnt depth-3 pipeline) ----
  const int row8 = lane >> 3;
  const int qs   = lane & 7;
  const int qoff = qs ^ row8;
  const float* xsrcA = x + (rowBase + (size_t)(8*w     + row8))*784 + qoff*4;
  const float* xsrcB = x + (rowBase + (size_t)(8*(w+4) + row8))*784 + qoff*4;
  const unsigned short* wsrc = Wcs + (16*w + (lane>>2))*32 + (lane&3)*8;

  const int rA0 = wr*32 + lr;
  const int sA0 = (2*lkg)     ^ (lr & 7);
  const int sA1 = (2*lkg + 1) ^ (lr & 7);
  const int offA00 = rA0*128 + sA0*16;
  const int offA01 = rA0*128 + sA1*16;
  const int rB0 = wc*32 + lr;
  const int sB  = lkg ^ ((rB0 >> 1) & 3);
  const int offB0 = rB0*64 + sB*16;

#define STAGE(slab, buf) do{                                                   \
    const int ks_ = (slab)*32;                                                 \
    char* xd_ = xsB  + (buf)*8192;                                             \
    char* wd_ = wcsB + (buf)*4096;                                             \
    const float* sa_ = (ks_ + qoff*4 < 784) ? (xsrcA + ks_) : zerog;           \
    const float* sb_ = (ks_ + qoff*4 < 784) ? (xsrcB + ks_) : zerog;           \
    gload_lds16(sa_, xd_ + w*1024);                                            \
    gload_lds16(sb_, xd_ + (w+4)*1024);                                        \
    gload_lds16(wsrc + (size_t)(slab)*2048, wd_ + w*1024);                     \
  }while(0)

  f32x4 acc00 = {}, acc01 = {}, acc10 = {}, acc11 = {};

#define BODY(tt, VMSTR) do{                                                    \
    asm volatile("s_waitcnt " VMSTR ::: "memory");                             \
    __builtin_amdgcn_sched_barrier(0);                                         \
    __builtin_amdgcn_s_barrier();                                              \
    const int cur_ = (tt) % 3;                                                 \
    const char* xb_ = xsB  + cur_*8192;                                        \
    const char* wb_ = wcsB + cur_*4096;                                        \
    f32x4 a00_ = *(const f32x4*)(xb_ + offA00);                                \
    f32x4 a01_ = *(const f32x4*)(xb_ + offA01);                                \
    f32x4 a10_ = *(const f32x4*)(xb_ + offA00 + 2048);                         \
    f32x4 a11_ = *(const f32x4*)(xb_ + offA01 + 2048);                         \
    bf16x8 b0_ = *(const bf16x8*)(wb_ + offB0);                                \
    bf16x8 b1_ = *(const bf16x8*)(wb_ + offB0 + 1024);                         \
    u32x4 pk0_ = { trunc_pk(a00_[0],a00_[1]), trunc_pk(a00_[2],a00_[3]),       \
                   trunc_pk(a01_[0],a01_[1]), trunc_pk(a01_[2],a01_[3]) };     \
    u32x4 pk1_ = { trunc_pk(a10_[0],a10_[1]), trunc_pk(a10_[2],a10_[3]),       \
                   trunc_pk(a11_[0],a11_[1]), trunc_pk(a11_[2],a11_[3]) };     \
    bf16x8 af0_ = __builtin_bit_cast(bf16x8, pk0_);                            \
    bf16x8 af1_ = __builtin_bit_cast(bf16x8, pk1_);                            \
    acc00 = __builtin_amdgcn_mfma_f32_16x16x32_bf16(af0_, b0_, acc00, 0,0,0);  \
    acc01 = __builtin_amdgcn_mfma_f32_16x16x32_bf16(af0_, b1_, acc01, 0,0,0);  \
    acc10 = __builtin_amdgcn_mfma_f32_16x16x32_bf16(af1_, b0_, acc10, 0,0,0);  \
    acc11 = __builtin_amdgcn_mfma_f32_16x16x32_bf16(af1_, b1_, acc11, 0,0,0);  \
    asm volatile("s_waitcnt lgkmcnt(0)" ::: "memory");                         \
    __builtin_amdgcn_sched_barrier(0);                                         \
    __builtin_amdgcn_s_barrier();                                              \
    if ((tt) + 3 < 25) STAGE((tt)+3, cur_);                                    \
  }while(0)

  STAGE(0, 0); STAGE(1, 1); STAGE(2, 2);

  for (int t = 0; t < 23; ++t)
    BODY(t, "vmcnt(6)");
  BODY(23, "vmcnt(3)");
  BODY(24, "vmcnt(0)");

#undef BODY
#undef STAGE

  // ---- epilogue: acc -> vlds (GEMM buffers dead after final barrier) ----
  {
    f32x4 accA[2][2] = { {acc00, acc01}, {acc10, acc11} };
    #pragma unroll
    for (int fj = 0; fj < 2; ++fj){
      const int col = wc*32 + fj*16 + lr;
      const float bc = bcomb[col];
      #pragma unroll
      for (int fi = 0; fi < 2; ++fi){
        const int r0 = wr*32 + fi*16 + lkg*4;
        #pragma unroll
        for (int j = 0; j < 4; ++j)
          vlds[(r0 + j)*76 + col] = accA[fi][fj][j] + bc;
      }
    }
  }
  for (int i = tid; i < 2048; i += 256) cW0aTS[i] = W0aT[i];
  __syncthreads();

  const int row = tid >> 2, p4 = tid & 3;

  // R1: v_tan0 = radial(v)  (in place)
  {
    f32x4 rv[4];
    float* vptr = &vlds[row*76 + p4*16];
    #pragma unroll
    for (int i = 0; i < 4; ++i) rv[i] = ((const f32x4*)vptr)[i];
    float ssq = 0.f;
    #pragma unroll
    for (int i = 0; i < 4; ++i)
      ssq += rv[i][0]*rv[i][0] + rv[i][1]*rv[i][1] + rv[i][2]*rv[i][2] + rv[i][3]*rv[i][3];
    ssq += __shfl_xor(ssq, 1); ssq += __shfl_xor(ssq, 2);
    const float fac = radial_factor(ssq, 1.0f, 1.0f);
    #pragma unroll
    for (int i = 0; i < 4; ++i){ rv[i] *= fac; ((f32x4*)vptr)[i] = rv[i]; }
  }
  __syncthreads();

  // R2: a0 = W0aE @ (2*vt0 - mb0) + b0a ; g0 = gelu(a0)
  {
    const int og = p4;
    float a0o[8];
    #pragma unroll
    for (int j = 0; j < 8; ++j) a0o[j] = cb0aS[og*8 + j];
    #pragma unroll 4
    for (int k = 0; k < 64; k += 4){
      f32x4 vtv = *(const f32x4*)&vlds[row*76 + k];
      f32x4 mm  = *(const f32x4*)&cmb0S[k];
      #pragma unroll
      for (int u = 0; u < 4; ++u){
        const float vc = 2.f*vtv[u] - mm[u];
        const f32x4* wp = (const f32x4*)&cW0aTS[(k+u)*32 + og*8];
        f32x4 w0 = wp[0], w1 = wp[1];
        #pragma unroll
        for (int j = 0; j < 4; ++j){ a0o[j] += w0[j]*vc; a0o[4+j] += w1[j]*vc; }
      }
    }
    #pragma unroll
    for (int j = 0; j < 8; ++j) gv[row*36 + og*8 + j] = gelu_f(a0o[j]);
  }
  __syncthreads();

  // R3: v1 = W0b@g0 + b0b; v_tan1, v_comb1
  {
    const int o1 = p4;
    float a1 = cb0bS[o1];
    #pragma unroll
    for (int k = 0; k < 32; k += 4){
      f32x4 gg = *(const f32x4*)&gv[row*36 + k];
      f32x4 ww = *(const f32x4*)&cW0bS[o1*32 + k];
      a1 += gg[0]*ww[0] + gg[1]*ww[1] + gg[2]*ww[2] + gg[3]*ww[3];
    }
    float ss1 = a1*a1;
    ss1 += __shfl_xor(ss1, 1); ss1 += __shfl_xor(ss1, 2);
    const float f1v = radial_factor(ss1, 0.8f, 0.8f);
    const float vt1 = a1*f1v;
    vlds[row*76 + 64 + o1] = vt1;
    vlds[row*76 + 68 + o1] = 2.f*vt1 - cmb1S[o1];
  }
  __syncthreads();

  // R4: a1 = W1aE @ vc1 + b1a ; g1 = gelu   (+ stage cW1b)
  for (int i = tid; i < 512; i += 256) cW1bS[i] = W1b[i];
  {
    const f32x4 vc1 = *(const f32x4*)&vlds[row*76 + 68];
    #pragma unroll
    for (int j = 0; j < 4; ++j){
      const int o = p4*4 + j;
      float s1 = cb1aS[o] + cW1aES[o*4+0]*vc1[0] + cW1aES[o*4+1]*vc1[1]
                          + cW1aES[o*4+2]*vc1[2] + cW1aES[o*4+3]*vc1[3];
      g1[row*20 + o] = gelu_f(s1);
    }
  }
  __syncthreads();

  // R5: v2 = W1b@g1 + b1b; v_tan2 -> gv
  {
    float v2[8]; float ss2 = 0.f;
    #pragma unroll
    for (int j = 0; j < 8; ++j){
      const int o = p4*8 + j;
      float s = cb1bS[o];
      #pragma unroll
      for (int k = 0; k < 16; k += 4){
        f32x4 gg = *(const f32x4*)&g1[row*20 + k];
        f32x4 ww = *(const f32x4*)&cW1bS[o*16 + k];
        s += gg[0]*ww[0] + gg[1]*ww[1] + gg[2]*ww[2] + gg[3]*ww[3];
      }
      v2[j] = s; ss2 += s*s;
    }
    ss2 += __shfl_xor(ss2, 1); ss2 += __shfl_xor(ss2, 2);
    const float f2v = radial_factor(ss2, 1.2f, 0.6f);
    #pragma unroll
    for (int j = 0; j < 8; ++j) gv[row*36 + p4*8 + j] = v2[j]*f2v;
  }
  __syncthreads();

  // R6: out = W_out @ concat(vt0, vt1, vt2) + b_out   (Wout from L2)
  for (int idx = tid; idx < 640; idx += 256){
    const int r6 = idx/10, o = idx - r6*10;
    float s = cboutS[o];
    const float* wrow = Wout + o*100;
    const float* vrow = &vlds[r6*76];
    #pragma unroll 4
    for (int k = 0; k < 68; k += 4){
      f32x4 a = *(const f32x4*)(vrow + k);
      f32x4 b = *(const f32x4*)(wrow + k);
      s += a[0]*b[0] + a[1]*b[1] + a[2]*b[2] + a[3]*b[3];
    }
    const float* v2row = &gv[r6*36];
    #pragma unroll 4
    for (int k = 0; k < 32; k += 4){
      f32x4 a = *(const f32x4*)(v2row + k);
      f32x4 b = *(const f32x4*)(wrow + 68 + k);
      s += a[0]*b[0] + a[1]*b[1] + a[2]*b[2] + a[3]*b[3];
    }
    out[(rowBase + (size_t)r6)*10 + o] = s;
  }
}

extern "C" void kernel_launch(void* const* d_in, const int* in_sizes, int n_in,
                              void* d_out, int out_size, void* d_ws, size_t ws_size,
                              hipStream_t stream)
{
  (void)n_in; (void)out_size; (void)ws_size;
  const float* x      = (const float*)d_in[0];
  const float* W_in   = (const float*)d_in[1];
  const float* b_in   = (const float*)d_in[2];
  const float* W_tan  = (const float*)d_in[3];
  const float* b_tan  = (const float*)d_in[4];
  const float* bp0    = (const float*)d_in[5];
  const float* bp1    = (const float*)d_in[6];
  /* bp2 = d_in[7] — dead in reference */
  const float* A_rot  = (const float*)d_in[8];
  const float* p_quat = (const float*)d_in[9];
  const float* q_quat = (const float*)d_in[10];
  const float* W0a    = (const float*)d_in[11];
  const float* b0a    = (const float*)d_in[12];
  const float* W0b    = (const float*)d_in[13];
  const float* b0b    = (const float*)d_in[14];
  const float* W1a    = (const float*)d_in[15];
  const float* b1a    = (const float*)d_in[16];
  const float* W1b    = (const float*)d_in[17];
  const float* b1b    = (const float*)d_in[18];
  const float* W_out  = (const float*)d_in[19];
  const float* b_out  = (const float*)d_in[20];

  char* ws = (char*)d_ws;
  unsigned short* Wcs = (unsigned short*)(ws + WS_WC);
  float* bcomb = (float*)(ws + WS_BCOMB);
  float* W0aE  = (float*)(ws + WS_W0AE);
  float* brot0 = (float*)(ws + WS_BROT0);
  float* bown0 = (float*)(ws + WS_BOWN0);
  float* W0aT  = (float*)(ws + WS_W0AT);
  float* mb0   = (float*)(ws + WS_MB0);
  float* mb1   = (float*)(ws + WS_MB1);
  float* W1aE  = (float*)(ws + WS_W1AE);
  float* zerog = (float*)(ws + WS_ZERO);

  const int Brows = in_sizes[0] / 784;
  const int nblk  = Brows / 64;

  prep_a<<<23, 256, 0, stream>>>(W_in, b_in, W_tan, b_tan, A_rot, W0a, bp0,
                                 Wcs, bcomb, W0aE, brot0, bown0, zerog);
  prep_small<<<1, 256, 0, stream>>>(bp1, p_quat, q_quat, b0a, W0b, b0b, W1a,
                                    W0aE, brot0, bown0, W0aT, mb0, mb1, W1aE);
  mega_fused<<<nblk, 256, 0, stream>>>(x, Wcs, bcomb, zerog, W0aT, mb0, mb1, W1aE,
                                       b0a, W0b, b0b, b1a, W1b, b1b,
                                       W_out, b_out, (float*)d_out);
}

// Round 14
// 77.331 us; speedup vs baseline: 1.2772x; 1.0071x over previous
//
#include <hip/hip_runtime.h>
#include <hip/hip_bf16.h>

typedef __attribute__((ext_vector_type(4))) float f32x4;
typedef __attribute__((ext_vector_type(2))) unsigned int u32x2;
typedef __attribute__((ext_vector_type(4))) unsigned int u32x4;
typedef __attribute__((ext_vector_type(8))) short bf16x8;

#define EPSF 1e-7f

__device__ __forceinline__ float radial_factor(float sumsq, float c, float s){
  float sc = sqrtf(c);
  float nv = sqrtf(sumsq);
  float nu = fmaxf(s*nv, EPSF);
  float th = tanhf(sc*nu);
  float r1 = th/sc;
  float maxn = (1.0f - 1e-5f)/sc;
  float r2 = fminf(r1, maxn);
  float n1 = fmaxf(r2, EPSF);
  float a  = fminf(sc*n1, 1.0f - 1e-7f);
  float r3 = 0.5f*logf((1.0f + a)/(1.0f - a));
  return r3*r2/(sc*n1*nu);
}

__device__ __forceinline__ float gelu_f(float x){
  return 0.5f*x*(1.0f + erff(x*0.70710678118654752f));
}

__device__ __forceinline__ unsigned f2bf1(float f){
  unsigned u = __float_as_uint(f);
  return (u + 0x7FFFu + ((u>>16)&1u)) >> 16;
}
__device__ __forceinline__ unsigned f2bf_pk(float lo, float hi){
  unsigned ul = f2bf1(lo);
  unsigned uh = __float_as_uint(hi);
  uh = (uh + 0x7FFFu + ((uh>>16)&1u)) & 0xFFFF0000u;
  return ul | uh;
}
// truncation pack via byte-select: D = {hi.b3, hi.b2, lo.b3, lo.b2} == (hi&0xFFFF0000)|(lo>>16)
__device__ __forceinline__ unsigned trunc_pk(float lo, float hi){
  return __builtin_amdgcn_perm(__float_as_uint(hi), __float_as_uint(lo), 0x07060302u);
}

__device__ __forceinline__ void gload_lds16(const void* g, void* l){
  __builtin_amdgcn_global_load_lds((const __attribute__((address_space(1))) unsigned int*)g,
                                   (__attribute__((address_space(3))) unsigned int*)l,
                                   16, 0, 0);
}

// ---------------- workspace layout (bytes) ----------------
#define WS_WC     0          // bf16 25*2048 elts (swizzled slabs)
#define WS_BCOMB  204800     // f32 [64]
#define WS_W0AE   205056     // f32 [32][64]
#define WS_BROT0  213248     // f32 [5][64]
#define WS_BOWN0  214528     // f32 [5][64]
#define WS_W0AT   215808     // f32 [64][32]
#define WS_MB0    224000     // f32 [64]
#define WS_MB1    224256     // f32 [4]
#define WS_W1AE   224272     // f32 [16][4]
#define WS_ZERO   224528     // f32 [16] zeros

// ============ prep A: blocks 0..12 = W_comb chunks (LDS-tiled); 13..22 = exp rows ============
__global__ __launch_bounds__(256) void prep_a(
    const float* __restrict__ W_in, const float* __restrict__ b_in,
    const float* __restrict__ W_tan, const float* __restrict__ b_tan,
    const float* __restrict__ A_rot, const float* __restrict__ W0a,
    const float* __restrict__ bp0,
    unsigned short* __restrict__ Wc, float* __restrict__ bcomb,
    float* __restrict__ W0aE, float* __restrict__ brot0, float* __restrict__ bown0,
    float* __restrict__ zerog)
{
  __shared__ __align__(16) float Wt[64][132];
  __shared__ __align__(16) float Wi[128][68];
  __shared__ float bin[128];
  __shared__ __align__(16) float Al[64][68];
  __shared__ __align__(16) float ST[64][68];
  const int bid = blockIdx.x, t = threadIdx.x;

  if (bid < 13){
    const int c = bid;
    for (int i = t; i < 2048; i += 256){
      const int n = i >> 5, s4 = i & 31;
      *(f32x4*)&Wt[n][s4*4] = *(const f32x4*)(W_tan + n*128 + s4*4);
    }
    for (int i = t; i < 2048; i += 256){
      const int j = i >> 4, s4 = i & 15;
      const int col = c*64 + s4*4;
      f32x4 v = {0.f,0.f,0.f,0.f};
      if (col < 784) v = *(const f32x4*)(W_in + j*784 + col);
      *(f32x4*)&Wi[j][s4*4] = v;
    }
    if (c == 0 && t < 128) bin[t] = b_in[t];
    __syncthreads();

    const int q  = t & 15;
    const int nb = t >> 4;
    #pragma unroll
    for (int i = 0; i < 4; ++i){
      const int n = nb*4 + i;
      f32x4 acc = {0.f,0.f,0.f,0.f};
      #pragma unroll 4
      for (int j = 0; j < 128; ++j)
        acc += Wt[n][j] * *(const f32x4*)&Wi[j][q*4];
      const int k4 = c*64 + q*4;
      if (k4 < 800){
        u32x2 st = { f2bf_pk(acc[0], acc[1]), f2bf_pk(acc[2], acc[3]) };
        const int tsl = k4 >> 5;
        const int qq  = (k4 >> 3) & 3;
        const int qp  = qq ^ ((n >> 1) & 3);
        const int idx = tsl*2048 + n*32 + qp*8 + (k4 & 7);
        *(u32x2*)(Wc + idx) = st;
      }
    }
    if (c == 0 && t < 64){
      float s = b_tan[t];
      for (int j = 0; j < 128; j += 4){
        f32x4 bb = *(const f32x4*)&bin[j];
        f32x4 ww = *(const f32x4*)&Wt[t][j];
        s += bb[0]*ww[0] + bb[1]*ww[1] + bb[2]*ww[2] + bb[3]*ww[3];
      }
      bcomb[t] = s;
    }
  } else {
    if (bid == 13 && t < 16) zerog[t] = 0.f;
    for (int m = t; m < 4096; m += 256){
      int r = m >> 6, cc = m & 63;
      Al[r][cc] = A_rot[m];
    }
    __syncthreads();
    for (int m = t; m < 4096; m += 256){
      int r = m >> 6, cc = m & 63;
      ST[r][cc] = Al[cc][r] - Al[r][cc];
    }
    __syncthreads();
    const int wv = t >> 6, lane = t & 63;
    const int row = (bid - 13)*4 + wv;     // 0..39, active < 37
    if (row < 37){
      float v, sgn;
      if (row < 32){ v = W0a[row*64 + lane]; sgn = 1.f; }
      else {
        const int r = row - 32;
        float b = bp0[r*64 + lane];
        float ssq = b*b;
        #pragma unroll
        for (int d = 1; d < 64; d <<= 1) ssq += __shfl_xor(ssq, d);
        float fc = radial_factor(ssq, 1.0f, 1.0f);
        v = b*fc;
        bown0[r*64 + lane] = v;
        sgn = -1.f;
      }
      float acc = v;
      for (int k = 1; k <= 12; ++k){
        const float coef = sgn/(float)k;
        float nv = 0.f;
        #pragma unroll
        for (int m = 0; m < 64; m += 4){
          f32x4 s4 = *(const f32x4*)&ST[lane][m];
          nv += __int_as_float(__builtin_amdgcn_readlane(__float_as_int(v), m+0))*s4[0];
          nv += __int_as_float(__builtin_amdgcn_readlane(__float_as_int(v), m+1))*s4[1];
          nv += __int_as_float(__builtin_amdgcn_readlane(__float_as_int(v), m+2))*s4[2];
          nv += __int_as_float(__builtin_amdgcn_readlane(__float_as_int(v), m+3))*s4[3];
        }
        nv *= coef;
        v = nv; acc += nv;
      }
      if (row < 32) W0aE[row*64 + lane] = acc;
      else          brot0[(row-32)*64 + lane] = acc;
    }
  }
}

// ============ prep B: small folds, once (1 block x 256), vectorized chains ============
__global__ __launch_bounds__(256) void prep_small(
    const float* __restrict__ bp1,
    const float* __restrict__ p_quat, const float* __restrict__ q_quat,
    const float* __restrict__ b0a, const float* __restrict__ W0b, const float* __restrict__ b0b,
    const float* __restrict__ W1a,
    const float* __restrict__ W0aE, const float* __restrict__ brot0, const float* __restrict__ bown0,
    float* __restrict__ W0aT, float* __restrict__ mb0, float* __restrict__ mb1,
    float* __restrict__ W1aE)
{
  __shared__ float g[5][32];
  __shared__ float c1[5][4];
  __shared__ float fac1[3];
  __shared__ float Mq[4][4];
  const int t = threadIdx.x;

  for (int i = t; i < 2048; i += 256){
    int o = i >> 6, k = i & 63;
    W0aT[k*32 + o] = W0aE[i];
  }
  if (t < 64){
    float s = 0.f;
    #pragma unroll
    for (int r = 0; r < 5; ++r) s += bown0[r*64 + t];
    mb0[t] = s * 0.2f;
  }
  if (t < 160){
    int r = t >> 5, o = t & 31;
    float s = b0a[o];
    #pragma unroll 4
    for (int k = 0; k < 64; k += 4){
      f32x4 bb = *(const f32x4*)(brot0 + r*64 + k);
      f32x4 ww = *(const f32x4*)(W0aE + o*64 + k);
      s += bb[0]*ww[0] + bb[1]*ww[1] + bb[2]*ww[2] + bb[3]*ww[3];
    }
    g[r][o] = gelu_f(s);
  }
  if (t >= 192 && t < 195){
    int r = t - 192;
    float ssq = 0.f;
    #pragma unroll
    for (int j = 0; j < 4; ++j){ float b = bp1[r*4+j]; ssq += b*b; }
    fac1[r] = radial_factor(ssq, 0.8f, 1.0f);
  }
  if (t == 224){
    float pw=p_quat[0],px=p_quat[1],py=p_quat[2],pz=p_quat[3];
    float n1 = sqrtf(pw*pw+px*px+py*py+pz*pz) + EPSF;
    pw/=n1; px/=n1; py/=n1; pz/=n1;
    float qw=q_quat[0],qx=q_quat[1],qy=q_quat[2],qz=q_quat[3];
    float n2 = sqrtf(qw*qw+qx*qx+qy*qy+qz*qz) + EPSF;
    qw/=n2; qx/=n2; qy/=n2; qz/=n2;
    float Lp[4][4] = {{pw,-px,-py,-pz},{px,pw,-pz,py},{py,pz,pw,-px},{pz,-py,px,pw}};
    float Rq[4][4] = {{qw,-qx,-qy,-qz},{qx,qw,qz,-qy},{qy,-qz,qw,qx},{qz,qy,-qx,qw}};
    #pragma unroll
    for (int i = 0; i < 4; ++i)
      #pragma unroll
      for (int k = 0; k < 4; ++k){
        float s = 0.f;
        #pragma unroll
        for (int m = 0; m < 4; ++m) s += Rq[i][m]*Lp[m][k];
        Mq[i][k] = s;
      }
  }
  __syncthreads();
  if (t < 20){
    int r = t >> 2, o = t & 3;
    float s = b0b[o];
    #pragma unroll
    for (int k = 0; k < 32; k += 4){
      f32x4 gg = *(const f32x4*)&g[r][k];
      f32x4 ww = *(const f32x4*)(W0b + o*32 + k);
      s += gg[0]*ww[0] + gg[1]*ww[1] + gg[2]*ww[2] + gg[3]*ww[3];
    }
    c1[r][o] = s;
  }
  __syncthreads();
  if (t < 4){
    float s = 0.f;
    #pragma unroll
    for (int r = 0; r < 3; ++r) s += bp1[r*4+t]*fac1[r];
    #pragma unroll
    for (int r = 0; r < 5; ++r) s += c1[r][t];
    mb1[t] = s * 0.125f;
  }
  if (t >= 64 && t < 128){
    int i = t - 64, o = i >> 2, kq = i & 3;
    float s = 0.f;
    #pragma unroll
    for (int j = 0; j < 4; ++j) s += W1a[o*4+j]*Mq[j][kq];
    W1aE[o*4+kq] = s;
  }
}

// ============ mega: counted-vmcnt GEMM -> row phase, 40.3KB LDS (4 blk/CU) ============
// LDS (bytes):
//   GEMM: xsB @0 [3][8192] | wcsB @24576 [3][4096] -> 36864
//   Row : vlds @0 [64][76] | gv @19456 [64][36] -> 28672
//         cW0aT @28672 [64][32] (R2 only) | g1 @28672 [64][20] (R4+, after barrier)
//   consts @36864..40352 (incl. cW1b @38304, staged at kernel start)
__global__ __launch_bounds__(256, 4) void mega_fused(
    const float* __restrict__ x,
    const unsigned short* __restrict__ Wcs,
    const float* __restrict__ bcomb,
    const float* __restrict__ zerog,
    const float* __restrict__ W0aT,
    const float* __restrict__ mb0g, const float* __restrict__ mb1g,
    const float* __restrict__ W1aEg,
    const float* __restrict__ b0a, const float* __restrict__ W0b, const float* __restrict__ b0b,
    const float* __restrict__ b1a, const float* __restrict__ W1b, const float* __restrict__ b1b,
    const float* __restrict__ Wout, const float* __restrict__ bout,
    float* __restrict__ out)
{
  __shared__ __align__(16) char smem[40352];
  char* xsB    = smem;                       // [3][8192]
  char* wcsB   = smem + 24576;               // [3][4096]
  float* vlds  = (float*)smem;               // stride 76
  float* gv    = (float*)(smem + 19456);     // stride 36
  float* cW0aTS= (float*)(smem + 28672);     // [64][32] (R2)
  float* g1    = (float*)(smem + 28672);     // stride 20 (R4+, after-R3 barrier protects)
  float* cmb0S  = (float*)(smem + 36864);
  float* cW0bS  = (float*)(smem + 37120);
  float* cW1aES = (float*)(smem + 37632);
  float* cb0aS  = (float*)(smem + 37888);
  float* cb0bS  = (float*)(smem + 38016);
  float* cmb1S  = (float*)(smem + 38032);
  float* cb1aS  = (float*)(smem + 38048);
  float* cb1bS  = (float*)(smem + 38112);
  float* cboutS = (float*)(smem + 38240);
  float* cW1bS  = (float*)(smem + 38304);    // [32][16] = 2048 -> 40352

  const int tid  = threadIdx.x;
  const int lane = tid & 63;
  const int w    = tid >> 6;
  const int wr   = w >> 1, wc = w & 1;
  const int lr   = lane & 15, lkg = lane >> 4;
  const size_t rowBase = (size_t)blockIdx.x * 64;

  // ---- stage all consts (region disjoint from GEMM buffers) ----
  if (tid < 64)  cmb0S[tid] = mb0g[tid];
  if (tid < 128) cW0bS[tid] = W0b[tid];
  if (tid < 64)  cW1aES[tid] = W1aEg[tid];
  if (tid < 32)  cb0aS[tid] = b0a[tid];
  if (tid < 4)   { cb0bS[tid] = b0b[tid]; cmb1S[tid] = mb1g[tid]; }
  if (tid < 16)  cb1aS[tid] = b1a[tid];
  if (tid < 32)  cb1bS[tid] = b1b[tid];
  if (tid < 10)  cboutS[tid] = bout[tid];
  for (int i = tid; i < 512; i += 256) cW1bS[i] = W1b[i];

  // ---- GEMM (counted-vmcnt depth-3 pipeline, fully unrolled) ----
  const int row8 = lane >> 3;
  const int qs   = lane & 7;
  const int qoff = qs ^ row8;
  const float* xsrcA = x + (rowBase + (size_t)(8*w     + row8))*784 + qoff*4;
  const float* xsrcB = x + (rowBase + (size_t)(8*(w+4) + row8))*784 + qoff*4;
  const unsigned short* wsrc = Wcs + (16*w + (lane>>2))*32 + (lane&3)*8;

  const int rA0 = wr*32 + lr;
  const int sA0 = (2*lkg)     ^ (lr & 7);
  const int sA1 = (2*lkg + 1) ^ (lr & 7);
  const int offA00 = rA0*128 + sA0*16;
  const int offA01 = rA0*128 + sA1*16;
  const int rB0 = wc*32 + lr;
  const int sB  = lkg ^ ((rB0 >> 1) & 3);
  const int offB0 = rB0*64 + sB*16;

#define STAGE(slab, buf) do{                                                   \
    const int ks_ = (slab)*32;                                                 \
    char* xd_ = xsB  + (buf)*8192;                                             \
    char* wd_ = wcsB + (buf)*4096;                                             \
    const float* sa_ = (ks_ + qoff*4 < 784) ? (xsrcA + ks_) : zerog;           \
    const float* sb_ = (ks_ + qoff*4 < 784) ? (xsrcB + ks_) : zerog;           \
    gload_lds16(sa_, xd_ + w*1024);                                            \
    gload_lds16(sb_, xd_ + (w+4)*1024);                                        \
    gload_lds16(wsrc + (size_t)(slab)*2048, wd_ + w*1024);                     \
  }while(0)

  f32x4 acc00 = {}, acc01 = {}, acc10 = {}, acc11 = {};

#define BODY(tt, VMSTR) do{                                                    \
    asm volatile("s_waitcnt " VMSTR ::: "memory");                             \
    __builtin_amdgcn_sched_barrier(0);                                         \
    __builtin_amdgcn_s_barrier();                                              \
    const int cur_ = (tt) % 3;                                                 \
    const char* xb_ = xsB  + cur_*8192;                                        \
    const char* wb_ = wcsB + cur_*4096;                                        \
    f32x4 a00_ = *(const f32x4*)(xb_ + offA00);                                \
    f32x4 a01_ = *(const f32x4*)(xb_ + offA01);                                \
    f32x4 a10_ = *(const f32x4*)(xb_ + offA00 + 2048);                         \
    f32x4 a11_ = *(const f32x4*)(xb_ + offA01 + 2048);                         \
    bf16x8 b0_ = *(const bf16x8*)(wb_ + offB0);                                \
    bf16x8 b1_ = *(const bf16x8*)(wb_ + offB0 + 1024);                         \
    u32x4 pk0_ = { trunc_pk(a00_[0],a00_[1]), trunc_pk(a00_[2],a00_[3]),       \
                   trunc_pk(a01_[0],a01_[1]), trunc_pk(a01_[2],a01_[3]) };     \
    u32x4 pk1_ = { trunc_pk(a10_[0],a10_[1]), trunc_pk(a10_[2],a10_[3]),       \
                   trunc_pk(a11_[0],a11_[1]), trunc_pk(a11_[2],a11_[3]) };     \
    bf16x8 af0_ = __builtin_bit_cast(bf16x8, pk0_);                            \
    bf16x8 af1_ = __builtin_bit_cast(bf16x8, pk1_);                            \
    acc00 = __builtin_amdgcn_mfma_f32_16x16x32_bf16(af0_, b0_, acc00, 0,0,0);  \
    acc01 = __builtin_amdgcn_mfma_f32_16x16x32_bf16(af0_, b1_, acc01, 0,0,0);  \
    acc10 = __builtin_amdgcn_mfma_f32_16x16x32_bf16(af1_, b0_, acc10, 0,0,0);  \
    acc11 = __builtin_amdgcn_mfma_f32_16x16x32_bf16(af1_, b1_, acc11, 0,0,0);  \
    asm volatile("s_waitcnt lgkmcnt(0)" ::: "memory");                         \
    __builtin_amdgcn_sched_barrier(0);                                         \
    __builtin_amdgcn_s_barrier();                                              \
    if ((tt) + 3 < 25) STAGE((tt)+3, cur_);                                    \
  }while(0)

  STAGE(0, 0); STAGE(1, 1); STAGE(2, 2);

  #pragma unroll
  for (int t = 0; t < 23; ++t)
    BODY(t, "vmcnt(6)");
  BODY(23, "vmcnt(3)");
  BODY(24, "vmcnt(0)");

#undef BODY
#undef STAGE

  // ---- epilogue: acc -> vlds; stage cW0aT (GEMM buffers dead) ----
  {
    f32x4 accA[2][2] = { {acc00, acc01}, {acc10, acc11} };
    #pragma unroll
    for (int fj = 0; fj < 2; ++fj){
      const int col = wc*32 + fj*16 + lr;
      const float bc = bcomb[col];
      #pragma unroll
      for (int fi = 0; fi < 2; ++fi){
        const int r0 = wr*32 + fi*16 + lkg*4;
        #pragma unroll
        for (int j = 0; j < 4; ++j)
          vlds[(r0 + j)*76 + col] = accA[fi][fj][j] + bc;
      }
    }
  }
  for (int i = tid; i < 2048; i += 256) cW0aTS[i] = W0aT[i];
  __syncthreads();   // B1: vlds + cW0aT cross-wave

  const int row = tid >> 2, p4 = tid & 3;
  // NOTE: R1..R5 dependencies are row-local; a row's 4 threads live in ONE wave,
  // so LDS RAW within the wave needs no __syncthreads. Barriers kept only where
  // cross-wave hazards exist (B1 above, B2 after R3 for g1-over-cW0aT alias,
  // B3 before R6 cross-row reads).

  // R1: v_tan0 = radial(v)  (in place)
  {
    f32x4 rv[4];
    float* vptr = &vlds[row*76 + p4*16];
    #pragma unroll
    for (int i = 0; i < 4; ++i) rv[i] = ((const f32x4*)vptr)[i];
    float ssq = 0.f;
    #pragma unroll
    for (int i = 0; i < 4; ++i)
      ssq += rv[i][0]*rv[i][0] + rv[i][1]*rv[i][1] + rv[i][2]*rv[i][2] + rv[i][3]*rv[i][3];
    ssq += __shfl_xor(ssq, 1); ssq += __shfl_xor(ssq, 2);
    const float fac = radial_factor(ssq, 1.0f, 1.0f);
    #pragma unroll
    for (int i = 0; i < 4; ++i){ rv[i] *= fac; ((f32x4*)vptr)[i] = rv[i]; }
  }

  // R2: a0 = W0aE @ (2*vt0 - mb0) + b0a ; g0 = gelu(a0)
  {
    const int og = p4;
    float a0o[8];
    #pragma unroll
    for (int j = 0; j < 8; ++j) a0o[j] = cb0aS[og*8 + j];
    #pragma unroll 4
    for (int k = 0; k < 64; k += 4){
      f32x4 vtv = *(const f32x4*)&vlds[row*76 + k];
      f32x4 mm  = *(const f32x4*)&cmb0S[k];
      #pragma unroll
      for (int u = 0; u < 4; ++u){
        const float vc = 2.f*vtv[u] - mm[u];
        const f32x4* wp = (const f32x4*)&cW0aTS[(k+u)*32 + og*8];
        f32x4 w0 = wp[0], w1 = wp[1];
        #pragma unroll
        for (int j = 0; j < 4; ++j){ a0o[j] += w0[j]*vc; a0o[4+j] += w1[j]*vc; }
      }
    }
    #pragma unroll
    for (int j = 0; j < 8; ++j) gv[row*36 + og*8 + j] = gelu_f(a0o[j]);
  }

  // R3: v1 = W0b@g0 + b0b; v_tan1, v_comb1
  {
    const int o1 = p4;
    float a1 = cb0bS[o1];
    #pragma unroll
    for (int k = 0; k < 32; k += 4){
      f32x4 gg = *(const f32x4*)&gv[row*36 + k];
      f32x4 ww = *(const f32x4*)&cW0bS[o1*32 + k];
      a1 += gg[0]*ww[0] + gg[1]*ww[1] + gg[2]*ww[2] + gg[3]*ww[3];
    }
    float ss1 = a1*a1;
    ss1 += __shfl_xor(ss1, 1); ss1 += __shfl_xor(ss1, 2);
    const float f1v = radial_factor(ss1, 0.8f, 0.8f);
    const float vt1 = a1*f1v;
    vlds[row*76 + 64 + o1] = vt1;
    vlds[row*76 + 68 + o1] = 2.f*vt1 - cmb1S[o1];
  }
  __syncthreads();   // B2: all waves past R2 (cW0aT reads) before g1 writes alias it

  // R4: a1 = W1aE @ vc1 + b1a ; g1 = gelu
  {
    const f32x4 vc1 = *(const f32x4*)&vlds[row*76 + 68];
    #pragma unroll
    for (int j = 0; j < 4; ++j){
      const int o = p4*4 + j;
      float s1 = cb1aS[o] + cW1aES[o*4+0]*vc1[0] + cW1aES[o*4+1]*vc1[1]
                          + cW1aES[o*4+2]*vc1[2] + cW1aES[o*4+3]*vc1[3];
      g1[row*20 + o] = gelu_f(s1);
    }
  }

  // R5: v2 = W1b@g1 + b1b; v_tan2 -> gv
  {
    float v2[8]; float ss2 = 0.f;
    #pragma unroll
    for (int j = 0; j < 8; ++j){
      const int o = p4*8 + j;
      float s = cb1bS[o];
      #pragma unroll
      for (int k = 0; k < 16; k += 4){
        f32x4 gg = *(const f32x4*)&g1[row*20 + k];
        f32x4 ww = *(const f32x4*)&cW1bS[o*16 + k];
        s += gg[0]*ww[0] + gg[1]*ww[1] + gg[2]*ww[2] + gg[3]*ww[3];
      }
      v2[j] = s; ss2 += s*s;
    }
    ss2 += __shfl_xor(ss2, 1); ss2 += __shfl_xor(ss2, 2);
    const float f2v = radial_factor(ss2, 1.2f, 0.6f);
    #pragma unroll
    for (int j = 0; j < 8; ++j) gv[row*36 + p4*8 + j] = v2[j]*f2v;
  }
  __syncthreads();   // B3: cross-row reads in R6

  // R6: out = W_out @ concat(vt0, vt1, vt2) + b_out   (Wout from L2)
  for (int idx = tid; idx < 640; idx += 256){
    const int r6 = idx/10, o = idx - r6*10;
    float s = cboutS[o];
    const float* wrow = Wout + o*100;
    const float* vrow = &vlds[r6*76];
    #pragma unroll 4
    for (int k = 0; k < 68; k += 4){
      f32x4 a = *(const f32x4*)(vrow + k);
      f32x4 b = *(const f32x4*)(wrow + k);
      s += a[0]*b[0] + a[1]*b[1] + a[2]*b[2] + a[3]*b[3];
    }
    const float* v2row = &gv[r6*36];
    #pragma unroll 4
    for (int k = 0; k < 32; k += 4){
      f32x4 a = *(const f32x4*)(v2row + k);
      f32x4 b = *(const f32x4*)(wrow + 68 + k);
      s += a[0]*b[0] + a[1]*b[1] + a[2]*b[2] + a[3]*b[3];
    }
    out[(rowBase + (size_t)r6)*10 + o] = s;
  }
}

extern "C" void kernel_launch(void* const* d_in, const int* in_sizes, int n_in,
                              void* d_out, int out_size, void* d_ws, size_t ws_size,
                              hipStream_t stream)
{
  (void)n_in; (void)out_size; (void)ws_size;
  const float* x      = (const float*)d_in[0];
  const float* W_in   = (const float*)d_in[1];
  const float* b_in   = (const float*)d_in[2];
  const float* W_tan  = (const float*)d_in[3];
  const float* b_tan  = (const float*)d_in[4];
  const float* bp0    = (const float*)d_in[5];
  const float* bp1    = (const float*)d_in[6];
  /* bp2 = d_in[7] — dead in reference */
  const float* A_rot  = (const float*)d_in[8];
  const float* p_quat = (const float*)d_in[9];
  const float* q_quat = (const float*)d_in[10];
  const float* W0a    = (const float*)d_in[11];
  const float* b0a    = (const float*)d_in[12];
  const float* W0b    = (const float*)d_in[13];
  const float* b0b    = (const float*)d_in[14];
  const float* W1a    = (const float*)d_in[15];
  const float* b1a    = (const float*)d_in[16];
  const float* W1b    = (const float*)d_in[17];
  const float* b1b    = (const float*)d_in[18];
  const float* W_out  = (const float*)d_in[19];
  const float* b_out  = (const float*)d_in[20];

  char* ws = (char*)d_ws;
  unsigned short* Wcs = (unsigned short*)(ws + WS_WC);
  float* bcomb = (float*)(ws + WS_BCOMB);
  float* W0aE  = (float*)(ws + WS_W0AE);
  float* brot0 = (float*)(ws + WS_BROT0);
  float* bown0 = (float*)(ws + WS_BOWN0);
  float* W0aT  = (float*)(ws + WS_W0AT);
  float* mb0   = (float*)(ws + WS_MB0);
  float* mb1   = (float*)(ws + WS_MB1);
  float* W1aE  = (float*)(ws + WS_W1AE);
  float* zerog = (float*)(ws + WS_ZERO);

  const int Brows = in_sizes[0] / 784;
  const int nblk  = Brows / 64;

  prep_a<<<23, 256, 0, stream>>>(W_in, b_in, W_tan, b_tan, A_rot, W0a, bp0,
                                 Wcs, bcomb, W0aE, brot0, bown0, zerog);
  prep_small<<<1, 256, 0, stream>>>(bp1, p_quat, q_quat, b0a, W0b, b0b, W1a,
                                    W0aE, brot0, bown0, W0aT, mb0, mb1, W1aE);
  mega_fused<<<nblk, 256, 0, stream>>>(x, Wcs, bcomb, zerog, W0aT, mb0, mb1, W1aE,
                                       b0a, W0b, b0b, b1a, W1b, b1b,
                                       W_out, b_out, (float*)d_out);
}